// Round 1
// baseline (505.872 us; speedup 1.0000x reference)
//
#include <hip/hip_runtime.h>
#include <hip/hip_bf16.h>

#define ALPHA2 0.04f   // leaky(leaky(x)) slope for x<0: 0.2*0.2

// ---------------- wa = W @ a  (384 outputs) ----------------
__global__ void k_wa(const float* __restrict__ W, const float* __restrict__ a,
                     float* __restrict__ wa) {
    int i = blockIdx.x * blockDim.x + threadIdx.x;
    if (i < 384) {
        float s = 0.f;
        #pragma unroll 8
        for (int u = 0; u < 128; ++u) s += W[i * 128 + u] * a[u];
        wa[i] = s;
    }
}

// ---------------- init per-entity state ----------------
__global__ void k_init(unsigned* __restrict__ segmax, float* __restrict__ denom,
                       int* __restrict__ count, int* __restrict__ cursor, int NE) {
    int i = blockIdx.x * blockDim.x + threadIdx.x;
    if (i < NE) { segmax[i] = 0u; denom[i] = 0.f; count[i] = 0; cursor[i] = 0; }
}

// ---------------- Out[nrows x 128] = In[nrows x 128] @ W[woff:woff+128, 0:128]
// 64x64 tile per block, 4x4 microtile, K=128 in one shot.
__global__ __launch_bounds__(256) void k_gemm(const float* __restrict__ In,
                                              const float* __restrict__ W, int woff,
                                              float* __restrict__ Out, int nrows) {
    __shared__ float Ash[128 * 64];  // [k][row]  (transposed)
    __shared__ float Wsh[128 * 64];  // [k][col]
    int tid = threadIdx.x;
    int rowbase = blockIdx.x * 64;
    int colbase = blockIdx.y * 64;

    // stage A (transpose): 64 rows x 128 k
    #pragma unroll
    for (int it = 0; it < 8; ++it) {
        int id = it * 256 + tid;           // 0..2047
        int k4 = id & 31, row = id >> 5;   // row 0..63
        int grow = rowbase + row;
        float4 v = make_float4(0.f, 0.f, 0.f, 0.f);
        if (grow < nrows) v = *(const float4*)(In + (size_t)grow * 128 + k4 * 4);
        int k = k4 * 4;
        Ash[(k + 0) * 64 + row] = v.x;
        Ash[(k + 1) * 64 + row] = v.y;
        Ash[(k + 2) * 64 + row] = v.z;
        Ash[(k + 3) * 64 + row] = v.w;
    }
    // stage W: 128 k x 64 cols
    #pragma unroll
    for (int it = 0; it < 8; ++it) {
        int id = it * 256 + tid;           // 0..2047
        int c4 = id & 15, k = id >> 4;     // k 0..127
        float4 v = *(const float4*)(W + (size_t)(woff + k) * 128 + colbase + c4 * 4);
        *(float4*)(Wsh + k * 64 + c4 * 4) = v;
    }
    __syncthreads();

    int tc = tid & 15, tr = tid >> 4;
    int r0 = tr * 4, c0 = tc * 4;
    float acc[4][4] = {};
    #pragma unroll 8
    for (int k = 0; k < 128; ++k) {
        float4 a4 = *(const float4*)(Ash + k * 64 + r0);
        float4 b4 = *(const float4*)(Wsh + k * 64 + c0);
        float av[4] = {a4.x, a4.y, a4.z, a4.w};
        float bv[4] = {b4.x, b4.y, b4.z, b4.w};
        #pragma unroll
        for (int i = 0; i < 4; ++i)
            #pragma unroll
            for (int j = 0; j < 4; ++j)
                acc[i][j] = fmaf(av[i], bv[j], acc[i][j]);
    }
    #pragma unroll
    for (int i = 0; i < 4; ++i) {
        int grow = rowbase + r0 + i;
        if (grow < nrows) {
            float4 o = make_float4(acc[i][0], acc[i][1], acc[i][2], acc[i][3]);
            *(float4*)(Out + (size_t)grow * 128 + colbase + c0) = o;
        }
    }
}

// ---------------- s1[n]=ent[n]·wa1, s3[n]=ent[n]·wa3 (one wave per row) -----
__global__ __launch_bounds__(256) void k_gemv_ent(const float* __restrict__ E,
                                                  int NE, const float* __restrict__ wa,
                                                  float* __restrict__ s1, float* __restrict__ s3) {
    int n = (blockIdx.x * blockDim.x + threadIdx.x) >> 6;
    int lane = threadIdx.x & 63;
    if (n >= NE) return;
    float2 e = *(const float2*)(E + (size_t)n * 128 + lane * 2);
    float2 w1 = *(const float2*)(wa + lane * 2);
    float2 w3 = *(const float2*)(wa + 256 + lane * 2);
    float d1 = e.x * w1.x + e.y * w1.y;
    float d3 = e.x * w3.x + e.y * w3.y;
    #pragma unroll
    for (int off = 32; off > 0; off >>= 1) {
        d1 += __shfl_down(d1, off);
        d3 += __shfl_down(d3, off);
    }
    if (lane == 0) { s1[n] = d1; s3[n] = d3; }
}

__global__ __launch_bounds__(256) void k_gemv_rel(const float* __restrict__ E,
                                                  int NR, const float* __restrict__ wa,
                                                  float* __restrict__ s2) {
    int n = (blockIdx.x * blockDim.x + threadIdx.x) >> 6;
    int lane = threadIdx.x & 63;
    if (n >= NR) return;
    float2 e = *(const float2*)(E + (size_t)n * 128 + lane * 2);
    float2 w2 = *(const float2*)(wa + 128 + lane * 2);
    float d2 = e.x * w2.x + e.y * w2.y;
    #pragma unroll
    for (int off = 32; off > 0; off >>= 1) d2 += __shfl_down(d2, off);
    if (lane == 0) s2[n] = d2;
}

// ---------------- per-edge score + segment max + degree count ----------------
__global__ void k_score(const int* __restrict__ h, const int* __restrict__ r,
                        const int* __restrict__ t, const float* __restrict__ s1,
                        const float* __restrict__ s2, const float* __restrict__ s3,
                        const float* __restrict__ a_b, float* __restrict__ score,
                        unsigned* __restrict__ segmax, int* __restrict__ count, int E) {
    int e = blockIdx.x * blockDim.x + threadIdx.x;
    if (e >= E) return;
    int hi = h[e];
    float x = s1[hi] + s2[r[e]] + s3[t[e]] + a_b[0];
    float sc = (x >= 0.f) ? x : ALPHA2 * x;
    score[e] = sc;
    unsigned u = __float_as_uint(sc);
    u = (u & 0x80000000u) ? ~u : (u | 0x80000000u);  // order-preserving encode
    atomicMax(segmax + hi, u);
    atomicAdd(count + hi, 1);
}

// ---------------- hierarchical exclusive scan of count -> rowstart ----------
__device__ __forceinline__ int block_incl_scan256(int s, int* sh, int t) {
    sh[t] = s; __syncthreads();
    #pragma unroll
    for (int off = 1; off < 256; off <<= 1) {
        int x = 0;
        if (t >= off) x = sh[t - off];
        __syncthreads();
        sh[t] += x;
        __syncthreads();
    }
    return sh[t];  // inclusive
}

__global__ __launch_bounds__(256) void k_scan_a(const int* __restrict__ count, int NE,
                                                int* __restrict__ bsum) {
    __shared__ int sh[256];
    int b = blockIdx.x, t = threadIdx.x;
    int base = b * 1024 + t * 4, s = 0;
    #pragma unroll
    for (int j = 0; j < 4; ++j) { int i = base + j; if (i < NE) s += count[i]; }
    sh[t] = s; __syncthreads();
    for (int off = 128; off > 0; off >>= 1) {
        if (t < off) sh[t] += sh[t + off];
        __syncthreads();
    }
    if (t == 0) bsum[b] = sh[0];
}

__global__ __launch_bounds__(256) void k_scan_b(int* __restrict__ bsum, int NB) {
    __shared__ int sh[256];
    int t = threadIdx.x;
    int v[4]; int s = 0;
    #pragma unroll
    for (int j = 0; j < 4; ++j) { int i = t * 4 + j; v[j] = (i < NB) ? bsum[i] : 0; s += v[j]; }
    int incl = block_incl_scan256(s, sh, t);
    int excl = incl - s;
    #pragma unroll
    for (int j = 0; j < 4; ++j) {
        int i = t * 4 + j;
        if (i < NB) { int tmp = v[j]; bsum[i] = excl; excl += tmp; }
    }
}

__global__ __launch_bounds__(256) void k_scan_c(const int* __restrict__ count, int NE,
                                                const int* __restrict__ bsum,
                                                int* __restrict__ rowstart, int E) {
    __shared__ int sh[256];
    int b = blockIdx.x, t = threadIdx.x;
    int base = b * 1024 + t * 4;
    int v[4]; int s = 0;
    #pragma unroll
    for (int j = 0; j < 4; ++j) { int i = base + j; v[j] = (i < NE) ? count[i] : 0; s += v[j]; }
    int incl = block_incl_scan256(s, sh, t);
    int excl = bsum[b] + incl - s;
    #pragma unroll
    for (int j = 0; j < 4; ++j) {
        int i = base + j;
        if (i < NE) { rowstart[i] = excl; excl += v[j]; }
    }
    if (b == 0 && t == 0) rowstart[NE] = E;
}

// ---------------- exp(score - max), denom, CSR scatter ----------------------
__global__ void k_expscatter(const int* __restrict__ h, const float* __restrict__ score,
                             const unsigned* __restrict__ segmax,
                             const int* __restrict__ rowstart, float* __restrict__ evalv,
                             float* __restrict__ denom, int* __restrict__ cursor,
                             int* __restrict__ edge_order, int E) {
    int e = blockIdx.x * blockDim.x + threadIdx.x;
    if (e >= E) return;
    int hi = h[e];
    unsigned u = segmax[hi];
    float m = (u & 0x80000000u) ? __uint_as_float(u ^ 0x80000000u) : __uint_as_float(~u);
    float ev = __expf(score[e] - m);
    evalv[e] = ev;
    atomicAdd(denom + hi, ev);
    int pos = atomicAdd(cursor + hi, 1);
    edge_order[rowstart[hi] + pos] = e;
}

// ---------------- per-entity aggregation: one wave per entity ---------------
__global__ __launch_bounds__(256) void k_aggregate(const int* __restrict__ rowstart,
                                                   const int* __restrict__ edge_order,
                                                   const float* __restrict__ evalv,
                                                   const int* __restrict__ r_index,
                                                   const int* __restrict__ t_index,
                                                   const float* __restrict__ P,
                                                   const float* __restrict__ Q,
                                                   const float* __restrict__ R,
                                                   const float* __restrict__ denom,
                                                   const float* __restrict__ bias,
                                                   float* __restrict__ out, int NE) {
    int n = (blockIdx.x * blockDim.x + threadIdx.x) >> 6;
    int lane = threadIdx.x & 63;
    if (n >= NE) return;
    int start = rowstart[n], end = rowstart[n + 1];
    int c0 = lane * 2;
    float2 acc = make_float2(0.f, 0.f);
    for (int i = start; i < end; ++i) {
        int e = edge_order[i];
        float ev = evalv[e];
        int r = r_index[e], t = t_index[e];
        float2 q = *(const float2*)(Q + (size_t)t * 128 + c0);
        float2 rr = *(const float2*)(R + (size_t)r * 128 + c0);
        acc.x = fmaf(ev, q.x + rr.x, acc.x);
        acc.y = fmaf(ev, q.y + rr.y, acc.y);
    }
    float2 bi = *(const float2*)(bias + c0);
    float2 o;
    if (end > start) {
        float inv = 1.f / denom[n];
        float2 p = *(const float2*)(P + (size_t)n * 128 + c0);
        o.x = p.x + acc.x * inv + bi.x;
        o.y = p.y + acc.y * inv + bi.y;
    } else {
        o = bi;
    }
    o.x = fmaxf(o.x, 0.f);
    o.y = fmaxf(o.y, 0.f);
    *(float2*)(out + (size_t)n * 128 + c0) = o;
}

// ============================================================================
static inline size_t align_up(size_t x, size_t a) { return (x + a - 1) / a * a; }

extern "C" void kernel_launch(void* const* d_in, const int* in_sizes, int n_in,
                              void* d_out, int out_size, void* d_ws, size_t ws_size,
                              hipStream_t stream) {
    const int* h_index = (const int*)d_in[0];
    const int* r_index = (const int*)d_in[1];
    const int* t_index = (const int*)d_in[2];
    const float* ent = (const float*)d_in[3];
    const float* rel = (const float*)d_in[4];
    const float* W = (const float*)d_in[5];
    const float* a = (const float*)d_in[6];
    const float* a_b = (const float*)d_in[7];
    const float* bias = (const float*)d_in[8];
    float* out = (float*)d_out;

    int E = in_sizes[0];
    int NE = in_sizes[3] / 128;
    int NR = in_sizes[4] / 128;

    char* p = (char*)d_ws;
    auto alloc = [&](size_t bytes) { char* q = p; p += align_up(bytes, 256); return (void*)q; };
    float* P = (float*)alloc((size_t)NE * 128 * 4);
    float* Q = (float*)alloc((size_t)NE * 128 * 4);
    float* Rm = (float*)alloc((size_t)NR * 128 * 4);
    float* wa = (float*)alloc(384 * 4);
    float* s1 = (float*)alloc((size_t)NE * 4);
    float* s3 = (float*)alloc((size_t)NE * 4);
    float* s2 = (float*)alloc((size_t)NR * 4);
    float* score = (float*)alloc((size_t)E * 4);
    float* evalv = (float*)alloc((size_t)E * 4);
    unsigned* segmax = (unsigned*)alloc((size_t)NE * 4);
    float* denom = (float*)alloc((size_t)NE * 4);
    int* count = (int*)alloc((size_t)NE * 4);
    int* cursor = (int*)alloc((size_t)NE * 4);
    int* rowstart = (int*)alloc((size_t)(NE + 1) * 4);
    int NB = (NE + 1023) / 1024;
    int* bsum = (int*)alloc((size_t)NB * 4);
    int* edge_order = (int*)alloc((size_t)E * 4);
    (void)ws_size; (void)n_in; (void)out_size;

    // 1. wa = W @ a
    k_wa<<<2, 256, 0, stream>>>(W, a, wa);
    // 2. init
    k_init<<<(NE + 255) / 256, 256, 0, stream>>>(segmax, denom, count, cursor, NE);
    // 3-5. P = ent@W1, Q = ent@W3, R = rel@W2
    k_gemm<<<dim3((NE + 63) / 64, 2), 256, 0, stream>>>(ent, W, 0, P, NE);
    k_gemm<<<dim3((NE + 63) / 64, 2), 256, 0, stream>>>(ent, W, 256, Q, NE);
    k_gemm<<<dim3((NR + 63) / 64, 2), 256, 0, stream>>>(rel, W, 128, Rm, NR);
    // 6-7. GEMVs for scores
    k_gemv_ent<<<(NE + 3) / 4, 256, 0, stream>>>(ent, NE, wa, s1, s3);
    k_gemv_rel<<<(NR + 3) / 4, 256, 0, stream>>>(rel, NR, wa, s2);
    // 8. per-edge score + segment max + count
    k_score<<<(E + 255) / 256, 256, 0, stream>>>(h_index, r_index, t_index, s1, s2, s3,
                                                 a_b, score, segmax, count, E);
    // 9-11. scan -> rowstart
    k_scan_a<<<NB, 256, 0, stream>>>(count, NE, bsum);
    k_scan_b<<<1, 256, 0, stream>>>(bsum, NB);
    k_scan_c<<<NB, 256, 0, stream>>>(count, NE, bsum, rowstart, E);
    // 12. exp + denom + scatter
    k_expscatter<<<(E + 255) / 256, 256, 0, stream>>>(h_index, score, segmax, rowstart,
                                                      evalv, denom, cursor, edge_order, E);
    // 13. aggregate + bias + relu
    k_aggregate<<<(NE + 3) / 4, 256, 0, stream>>>(rowstart, edge_order, evalv, r_index,
                                                  t_index, P, Q, Rm, denom, bias, out, NE);
}

// Round 2
// 445.760 us; speedup vs baseline: 1.1349x; 1.1349x over previous
//
#include <hip/hip_runtime.h>
#include <hip/hip_bf16.h>

#define ALPHA2 0.04f   // leaky(leaky(x)) slope for x<0: 0.2*0.2

// ---- bf16 helpers (raw round-to-nearest-even; values are finite) ----
__device__ __forceinline__ unsigned short f2bf(float f) {
    unsigned u = __float_as_uint(f);
    unsigned r = (u + 0x7fffu + ((u >> 16) & 1u)) >> 16;
    return (unsigned short)r;
}
__device__ __forceinline__ float bf2f(unsigned short h) {
    return __uint_as_float((unsigned)h << 16);
}

// ---------------- init per-entity state ----------------
__global__ void k_init(float* __restrict__ denom, int* __restrict__ count,
                       int* __restrict__ cursor, float* __restrict__ s1,
                       float* __restrict__ s3, float* __restrict__ s2,
                       int NE, int NR) {
    int i = blockIdx.x * blockDim.x + threadIdx.x;
    if (i < NE) { denom[i] = 0.f; count[i] = 0; cursor[i] = 0; s1[i] = 0.f; s3[i] = 0.f; }
    if (i < NR) { s2[i] = 0.f; }
}

// ---------------- Out[nrows x 128] = In[nrows x 128] @ W[woff:woff+128, :]
// 64x64 tile / block, 4x4 microtile. Epilogue: fused row-dot with avec ->
// atomicAdd(svec[row]) (computes s = (In@Wk)·a without a separate pass),
// and output stored fp32 or bf16.
template <bool BF16OUT>
__global__ __launch_bounds__(256) void k_gemm(const float* __restrict__ In,
                                              const float* __restrict__ W, int woff,
                                              float* __restrict__ OutF,
                                              unsigned short* __restrict__ OutB,
                                              int nrows,
                                              const float* __restrict__ avec,
                                              float* __restrict__ svec) {
    __shared__ float Ash[128 * 64];  // [k][row]  (transposed)
    __shared__ float Wsh[128 * 64];  // [k][col]
    int tid = threadIdx.x;
    int rowbase = blockIdx.x * 64;
    int colbase = blockIdx.y * 64;

    #pragma unroll
    for (int it = 0; it < 8; ++it) {
        int id = it * 256 + tid;
        int k4 = id & 31, row = id >> 5;
        int grow = rowbase + row;
        float4 v = make_float4(0.f, 0.f, 0.f, 0.f);
        if (grow < nrows) v = *(const float4*)(In + (size_t)grow * 128 + k4 * 4);
        int k = k4 * 4;
        Ash[(k + 0) * 64 + row] = v.x;
        Ash[(k + 1) * 64 + row] = v.y;
        Ash[(k + 2) * 64 + row] = v.z;
        Ash[(k + 3) * 64 + row] = v.w;
    }
    #pragma unroll
    for (int it = 0; it < 8; ++it) {
        int id = it * 256 + tid;
        int c4 = id & 15, k = id >> 4;
        float4 v = *(const float4*)(W + (size_t)(woff + k) * 128 + colbase + c4 * 4);
        *(float4*)(Wsh + k * 64 + c4 * 4) = v;
    }
    __syncthreads();

    int tc = tid & 15, tr = tid >> 4;
    int r0 = tr * 4, c0 = tc * 4;
    float acc[4][4] = {};
    #pragma unroll 8
    for (int k = 0; k < 128; ++k) {
        float4 a4 = *(const float4*)(Ash + k * 64 + r0);
        float4 b4 = *(const float4*)(Wsh + k * 64 + c0);
        float av[4] = {a4.x, a4.y, a4.z, a4.w};
        float bv[4] = {b4.x, b4.y, b4.z, b4.w};
        #pragma unroll
        for (int i = 0; i < 4; ++i)
            #pragma unroll
            for (int j = 0; j < 4; ++j)
                acc[i][j] = fmaf(av[i], bv[j], acc[i][j]);
    }

    // fused s = row · avec (this block's 64-col slice; 16 lanes share a row)
    float av0 = avec[colbase + c0 + 0], av1 = avec[colbase + c0 + 1];
    float av2 = avec[colbase + c0 + 2], av3 = avec[colbase + c0 + 3];

    #pragma unroll
    for (int i = 0; i < 4; ++i) {
        int grow = rowbase + r0 + i;
        float part = acc[i][0] * av0 + acc[i][1] * av1 + acc[i][2] * av2 + acc[i][3] * av3;
        #pragma unroll
        for (int off = 1; off < 16; off <<= 1) part += __shfl_xor(part, off);
        if (grow < nrows) {
            if (tc == 0) atomicAdd(svec + grow, part);
            if (BF16OUT) {
                unsigned short b[4] = {f2bf(acc[i][0]), f2bf(acc[i][1]),
                                       f2bf(acc[i][2]), f2bf(acc[i][3])};
                ushort4 u; u.x = b[0]; u.y = b[1]; u.z = b[2]; u.w = b[3];
                *(ushort4*)(OutB + (size_t)grow * 128 + colbase + c0) = u;
            } else {
                float4 o = make_float4(acc[i][0], acc[i][1], acc[i][2], acc[i][3]);
                *(float4*)(OutF + (size_t)grow * 128 + colbase + c0) = o;
            }
        }
    }
}

// ---------------- per-edge: score -> exp (no max shift; |score| <~ 6),
// denom accumulate, degree count ----------------
__global__ void k_score(const int* __restrict__ h, const int* __restrict__ r,
                        const int* __restrict__ t, const float* __restrict__ s1,
                        const float* __restrict__ s2, const float* __restrict__ s3,
                        const float* __restrict__ a_b, float* __restrict__ evalv,
                        float* __restrict__ denom, int* __restrict__ count, int E) {
    int e = blockIdx.x * blockDim.x + threadIdx.x;
    if (e >= E) return;
    int hi = h[e];
    float x = s1[hi] + s2[r[e]] + s3[t[e]] + a_b[0];
    float sc = (x >= 0.f) ? x : ALPHA2 * x;
    float ev = __expf(sc);
    evalv[e] = ev;
    atomicAdd(denom + hi, ev);
    atomicAdd(count + hi, 1);
}

// ---------------- hierarchical exclusive scan of count -> rowstart ----------
__device__ __forceinline__ int block_incl_scan256(int s, int* sh, int t) {
    sh[t] = s; __syncthreads();
    #pragma unroll
    for (int off = 1; off < 256; off <<= 1) {
        int x = 0;
        if (t >= off) x = sh[t - off];
        __syncthreads();
        sh[t] += x;
        __syncthreads();
    }
    return sh[t];
}

__global__ __launch_bounds__(256) void k_scan_a(const int* __restrict__ count, int NE,
                                                int* __restrict__ bsum) {
    __shared__ int sh[256];
    int b = blockIdx.x, t = threadIdx.x;
    int base = b * 1024 + t * 4, s = 0;
    #pragma unroll
    for (int j = 0; j < 4; ++j) { int i = base + j; if (i < NE) s += count[i]; }
    sh[t] = s; __syncthreads();
    for (int off = 128; off > 0; off >>= 1) {
        if (t < off) sh[t] += sh[t + off];
        __syncthreads();
    }
    if (t == 0) bsum[b] = sh[0];
}

__global__ __launch_bounds__(256) void k_scan_b(int* __restrict__ bsum, int NB) {
    __shared__ int sh[256];
    int t = threadIdx.x;
    int v[4]; int s = 0;
    #pragma unroll
    for (int j = 0; j < 4; ++j) { int i = t * 4 + j; v[j] = (i < NB) ? bsum[i] : 0; s += v[j]; }
    int incl = block_incl_scan256(s, sh, t);
    int excl = incl - s;
    #pragma unroll
    for (int j = 0; j < 4; ++j) {
        int i = t * 4 + j;
        if (i < NB) { int tmp = v[j]; bsum[i] = excl; excl += tmp; }
    }
}

__global__ __launch_bounds__(256) void k_scan_c(const int* __restrict__ count, int NE,
                                                const int* __restrict__ bsum,
                                                int* __restrict__ rowstart, int E) {
    __shared__ int sh[256];
    int b = blockIdx.x, t = threadIdx.x;
    int base = b * 1024 + t * 4;
    int v[4]; int s = 0;
    #pragma unroll
    for (int j = 0; j < 4; ++j) { int i = base + j; v[j] = (i < NE) ? count[i] : 0; s += v[j]; }
    int incl = block_incl_scan256(s, sh, t);
    int excl = bsum[b] + incl - s;
    #pragma unroll
    for (int j = 0; j < 4; ++j) {
        int i = base + j;
        if (i < NE) { rowstart[i] = excl; excl += v[j]; }
    }
    if (b == 0 && t == 0) rowstart[NE] = E;
}

// ---------------- CSR scatter: segment-sorted packed {r,t} + ev -------------
__global__ void k_scatter(const int* __restrict__ h, const int* __restrict__ r,
                          const int* __restrict__ t, const float* __restrict__ evalv,
                          const int* __restrict__ rowstart, int* __restrict__ cursor,
                          int2* __restrict__ rt_s, float* __restrict__ ev_s, int E) {
    int e = blockIdx.x * blockDim.x + threadIdx.x;
    if (e >= E) return;
    int hi = h[e];
    int pos = atomicAdd(cursor + hi, 1);
    int idx = rowstart[hi] + pos;
    rt_s[idx] = make_int2(r[e], t[e]);
    ev_s[idx] = evalv[e];
}

// ---------------- per-entity aggregation: one wave per entity ---------------
__global__ __launch_bounds__(256) void k_aggregate(const int* __restrict__ rowstart,
                                                   const int2* __restrict__ rt_s,
                                                   const float* __restrict__ ev_s,
                                                   const float* __restrict__ P,
                                                   const unsigned short* __restrict__ Qb,
                                                   const unsigned short* __restrict__ Rb,
                                                   const float* __restrict__ denom,
                                                   const float* __restrict__ bias,
                                                   float* __restrict__ out, int NE) {
    int n = (blockIdx.x * blockDim.x + threadIdx.x) >> 6;
    int lane = threadIdx.x & 63;
    if (n >= NE) return;
    int start = rowstart[n], end = rowstart[n + 1];
    int c0 = lane * 2;
    float2 acc = make_float2(0.f, 0.f);
    for (int i = start; i < end; ++i) {
        int2 rt = rt_s[i];
        float ev = ev_s[i];
        ushort2 q = *(const ushort2*)(Qb + (size_t)rt.y * 128 + c0);
        ushort2 rr = *(const ushort2*)(Rb + (size_t)rt.x * 128 + c0);
        acc.x = fmaf(ev, bf2f(q.x) + bf2f(rr.x), acc.x);
        acc.y = fmaf(ev, bf2f(q.y) + bf2f(rr.y), acc.y);
    }
    float2 bi = *(const float2*)(bias + c0);
    float2 o;
    if (end > start) {
        float inv = 1.f / denom[n];
        float2 p = *(const float2*)(P + (size_t)n * 128 + c0);
        o.x = p.x + acc.x * inv + bi.x;
        o.y = p.y + acc.y * inv + bi.y;
    } else {
        o = bi;
    }
    o.x = fmaxf(o.x, 0.f);
    o.y = fmaxf(o.y, 0.f);
    *(float2*)(out + (size_t)n * 128 + c0) = o;
}

// ============================================================================
static inline size_t align_up(size_t x, size_t a) { return (x + a - 1) / a * a; }

extern "C" void kernel_launch(void* const* d_in, const int* in_sizes, int n_in,
                              void* d_out, int out_size, void* d_ws, size_t ws_size,
                              hipStream_t stream) {
    const int* h_index = (const int*)d_in[0];
    const int* r_index = (const int*)d_in[1];
    const int* t_index = (const int*)d_in[2];
    const float* ent = (const float*)d_in[3];
    const float* rel = (const float*)d_in[4];
    const float* W = (const float*)d_in[5];
    const float* a = (const float*)d_in[6];
    const float* a_b = (const float*)d_in[7];
    const float* bias = (const float*)d_in[8];
    float* out = (float*)d_out;

    int E = in_sizes[0];
    int NE = in_sizes[3] / 128;
    int NR = in_sizes[4] / 128;

    char* p = (char*)d_ws;
    auto alloc = [&](size_t bytes) { char* q = p; p += align_up(bytes, 256); return (void*)q; };
    float* P = (float*)alloc((size_t)NE * 128 * 4);
    unsigned short* Qb = (unsigned short*)alloc((size_t)NE * 128 * 2);
    unsigned short* Rb = (unsigned short*)alloc((size_t)NR * 128 * 2);
    float* s1 = (float*)alloc((size_t)NE * 4);
    float* s3 = (float*)alloc((size_t)NE * 4);
    float* s2 = (float*)alloc((size_t)NR * 4);
    float* evalv = (float*)alloc((size_t)E * 4);
    float* denom = (float*)alloc((size_t)NE * 4);
    int* count = (int*)alloc((size_t)NE * 4);
    int* cursor = (int*)alloc((size_t)NE * 4);
    int* rowstart = (int*)alloc((size_t)(NE + 1) * 4);
    int NB = (NE + 1023) / 1024;
    int* bsum = (int*)alloc((size_t)NB * 4);
    int2* rt_s = (int2*)alloc((size_t)E * 8);
    float* ev_s = (float*)alloc((size_t)E * 4);
    (void)ws_size; (void)n_in; (void)out_size;

    // 1. init atomic targets
    k_init<<<(NE + 255) / 256, 256, 0, stream>>>(denom, count, cursor, s1, s3, s2, NE, NR);
    // 2-4. P = ent@W1 (fp32, +s1), Qb = ent@W3 (bf16, +s3), Rb = rel@W2 (bf16, +s2)
    k_gemm<false><<<dim3((NE + 63) / 64, 2), 256, 0, stream>>>(ent, W, 0, P, nullptr, NE, a, s1);
    k_gemm<true><<<dim3((NE + 63) / 64, 2), 256, 0, stream>>>(ent, W, 256, nullptr, Qb, NE, a, s3);
    k_gemm<true><<<dim3((NR + 63) / 64, 2), 256, 0, stream>>>(rel, W, 128, nullptr, Rb, NR, a, s2);
    // 5. per-edge score -> exp -> denom + count
    k_score<<<(E + 255) / 256, 256, 0, stream>>>(h_index, r_index, t_index, s1, s2, s3,
                                                 a_b, evalv, denom, count, E);
    // 6-8. scan -> rowstart
    k_scan_a<<<NB, 256, 0, stream>>>(count, NE, bsum);
    k_scan_b<<<1, 256, 0, stream>>>(bsum, NB);
    k_scan_c<<<NB, 256, 0, stream>>>(count, NE, bsum, rowstart, E);
    // 9. CSR scatter of packed edge data
    k_scatter<<<(E + 255) / 256, 256, 0, stream>>>(h_index, r_index, t_index, evalv,
                                                   rowstart, cursor, rt_s, ev_s, E);
    // 10. aggregate + bias + relu
    k_aggregate<<<(NE + 3) / 4, 256, 0, stream>>>(rowstart, rt_s, ev_s, P, Qb, Rb,
                                                  denom, bias, out, NE);
}

// Round 3
// 314.241 us; speedup vs baseline: 1.6098x; 1.4185x over previous
//
#include <hip/hip_runtime.h>
#include <hip/hip_bf16.h>

#define ALPHA2 0.04f   // leaky(leaky(x)) slope for x<0: 0.2*0.2

typedef __attribute__((ext_vector_type(8))) short short8;
typedef __attribute__((ext_vector_type(4))) float floatx4;

// ---- bf16 helpers (raw round-to-nearest-even; values are finite) ----
__device__ __forceinline__ unsigned short f2bf(float f) {
    unsigned u = __float_as_uint(f);
    unsigned r = (u + 0x7fffu + ((u >> 16) & 1u)) >> 16;
    return (unsigned short)r;
}
__device__ __forceinline__ float bf2f(unsigned short h) {
    return __uint_as_float((unsigned)h << 16);
}

// ---------------- fp32 -> bf16 cast (4 elems/thread) ----------------
__global__ void k_cast(const float* __restrict__ in, unsigned short* __restrict__ out, int n4) {
    int i = blockIdx.x * blockDim.x + threadIdx.x;
    if (i >= n4) return;
    float4 v = ((const float4*)in)[i];
    ushort4 u;
    u.x = f2bf(v.x); u.y = f2bf(v.y); u.z = f2bf(v.z); u.w = f2bf(v.w);
    ((ushort4*)out)[i] = u;
}

// ---------------- W [384][128] fp32 -> Wt [128][384] bf16 (transposed) ------
__global__ void k_wt(const float* __restrict__ W, unsigned short* __restrict__ Wt) {
    int idx = blockIdx.x * blockDim.x + threadIdx.x;
    if (idx >= 384 * 128) return;
    int k = idx >> 7, n = idx & 127;
    Wt[n * 384 + k] = f2bf(W[idx]);
}

// ---------------- init per-entity atomic targets ----------------
__global__ void k_init(float* __restrict__ denom, int* __restrict__ count,
                       int* __restrict__ cursor, int NE) {
    int i = blockIdx.x * blockDim.x + threadIdx.x;
    if (i < NE) { denom[i] = 0.f; count[i] = 0; cursor[i] = 0; }
}

// ---------------- MFMA GEMM: Out[nrows x 128] = Abf @ W[woff..woff+128, :]
// 128-row block, 4 waves, each wave 32 rows x 128 cols via 16x16x32 bf16 MFMA.
// Epilogue: svec[row] = out_row · avec (no atomics: wave owns complete rows).
#define LDA 136  // bf16 row stride in LDS (128 + 8 pad -> conflict-free b128)

template <bool BF16OUT>
__global__ __launch_bounds__(256) void k_mfma_gemm(
        const unsigned short* __restrict__ Abf,  // [nrows][128] bf16
        const unsigned short* __restrict__ Wt,   // [128][384] bf16 (n-major)
        int woff,
        float* __restrict__ OutF, unsigned short* __restrict__ OutB,
        int nrows, const float* __restrict__ avec, float* __restrict__ svec) {
    __shared__ unsigned short Ash[128 * LDA];
    __shared__ unsigned short Wsh[128 * LDA];
    int tid = threadIdx.x;
    int rowbase = blockIdx.x * 128;

    // stage A: 128 rows x 16 chunks of 8 bf16 (16B each)
    #pragma unroll
    for (int it = 0; it < 8; ++it) {
        int id = it * 256 + tid;
        int chunk = id & 15, row = id >> 4;
        int grow = rowbase + row;
        if (grow > nrows - 1) grow = nrows - 1;  // clamp: garbage rows masked at store
        uint4 v = *(const uint4*)(Abf + (size_t)grow * 128 + chunk * 8);
        *(uint4*)(Ash + row * LDA + chunk * 8) = v;
    }
    // stage Wt slice: Wsh[n][k'] = Wt[n][woff + k']
    #pragma unroll
    for (int it = 0; it < 8; ++it) {
        int id = it * 256 + tid;
        int chunk = id & 15, n = id >> 4;
        uint4 v = *(const uint4*)(Wt + (size_t)n * 384 + woff + chunk * 8);
        *(uint4*)(Wsh + n * LDA + chunk * 8) = v;
    }
    __syncthreads();

    int wave = tid >> 6, lane = tid & 63;
    int m16 = lane & 15, quad = lane >> 4;
    int rs = wave * 32;

    floatx4 acc[2][8];
    #pragma unroll
    for (int i = 0; i < 2; ++i)
        #pragma unroll
        for (int j = 0; j < 8; ++j) acc[i][j] = (floatx4){0.f, 0.f, 0.f, 0.f};

    #pragma unroll
    for (int kc = 0; kc < 4; ++kc) {
        short8 af[2], bf[8];
        #pragma unroll
        for (int i = 0; i < 2; ++i)
            af[i] = *(const short8*)(Ash + (rs + i * 16 + m16) * LDA + kc * 32 + quad * 8);
        #pragma unroll
        for (int j = 0; j < 8; ++j)
            bf[j] = *(const short8*)(Wsh + (j * 16 + m16) * LDA + kc * 32 + quad * 8);
        #pragma unroll
        for (int i = 0; i < 2; ++i)
            #pragma unroll
            for (int j = 0; j < 8; ++j)
                acc[i][j] = __builtin_amdgcn_mfma_f32_16x16x32_bf16(af[i], bf[j], acc[i][j], 0, 0, 0);
    }

    // epilogue: C/D layout col=lane&15, row=quad*4+reg
    float av[8];
    #pragma unroll
    for (int j = 0; j < 8; ++j) av[j] = avec[j * 16 + m16];
    #pragma unroll
    for (int i = 0; i < 2; ++i) {
        #pragma unroll
        for (int reg = 0; reg < 4; ++reg) {
            int row = rowbase + rs + i * 16 + quad * 4 + reg;
            bool ok = row < nrows;
            float part = 0.f;
            #pragma unroll
            for (int j = 0; j < 8; ++j) {
                float v = acc[i][j][reg];
                part = fmaf(v, av[j], part);
                if (ok) {
                    int col = j * 16 + m16;
                    if (BF16OUT) OutB[(size_t)row * 128 + col] = f2bf(v);
                    else         OutF[(size_t)row * 128 + col] = v;
                }
            }
            #pragma unroll
            for (int off = 1; off < 16; off <<= 1) part += __shfl_xor(part, off);
            if (ok && m16 == 0) svec[row] = part;
        }
    }
}

// ---------------- per-edge: score -> exp (no max shift; |score| <~ 6),
// denom accumulate, degree count ----------------
__global__ void k_score(const int* __restrict__ h, const int* __restrict__ r,
                        const int* __restrict__ t, const float* __restrict__ s1,
                        const float* __restrict__ s2, const float* __restrict__ s3,
                        const float* __restrict__ a_b, float* __restrict__ evalv,
                        float* __restrict__ denom, int* __restrict__ count, int E) {
    int e = blockIdx.x * blockDim.x + threadIdx.x;
    if (e >= E) return;
    int hi = h[e];
    float x = s1[hi] + s2[r[e]] + s3[t[e]] + a_b[0];
    float sc = (x >= 0.f) ? x : ALPHA2 * x;
    float ev = __expf(sc);
    evalv[e] = ev;
    atomicAdd(denom + hi, ev);
    atomicAdd(count + hi, 1);
}

// ---------------- hierarchical exclusive scan of count -> rowstart ----------
__device__ __forceinline__ int block_incl_scan256(int s, int* sh, int t) {
    sh[t] = s; __syncthreads();
    #pragma unroll
    for (int off = 1; off < 256; off <<= 1) {
        int x = 0;
        if (t >= off) x = sh[t - off];
        __syncthreads();
        sh[t] += x;
        __syncthreads();
    }
    return sh[t];
}

__global__ __launch_bounds__(256) void k_scan_a(const int* __restrict__ count, int NE,
                                                int* __restrict__ bsum) {
    __shared__ int sh[256];
    int b = blockIdx.x, t = threadIdx.x;
    int base = b * 1024 + t * 4, s = 0;
    #pragma unroll
    for (int j = 0; j < 4; ++j) { int i = base + j; if (i < NE) s += count[i]; }
    sh[t] = s; __syncthreads();
    for (int off = 128; off > 0; off >>= 1) {
        if (t < off) sh[t] += sh[t + off];
        __syncthreads();
    }
    if (t == 0) bsum[b] = sh[0];
}

__global__ __launch_bounds__(256) void k_scan_b(int* __restrict__ bsum, int NB) {
    __shared__ int sh[256];
    int t = threadIdx.x;
    int v[4]; int s = 0;
    #pragma unroll
    for (int j = 0; j < 4; ++j) { int i = t * 4 + j; v[j] = (i < NB) ? bsum[i] : 0; s += v[j]; }
    int incl = block_incl_scan256(s, sh, t);
    int excl = incl - s;
    #pragma unroll
    for (int j = 0; j < 4; ++j) {
        int i = t * 4 + j;
        if (i < NB) { int tmp = v[j]; bsum[i] = excl; excl += tmp; }
    }
}

__global__ __launch_bounds__(256) void k_scan_c(const int* __restrict__ count, int NE,
                                                const int* __restrict__ bsum,
                                                int* __restrict__ rowstart, int E) {
    __shared__ int sh[256];
    int b = blockIdx.x, t = threadIdx.x;
    int base = b * 1024 + t * 4;
    int v[4]; int s = 0;
    #pragma unroll
    for (int j = 0; j < 4; ++j) { int i = base + j; v[j] = (i < NE) ? count[i] : 0; s += v[j]; }
    int incl = block_incl_scan256(s, sh, t);
    int excl = bsum[b] + incl - s;
    #pragma unroll
    for (int j = 0; j < 4; ++j) {
        int i = base + j;
        if (i < NE) { rowstart[i] = excl; excl += v[j]; }
    }
    if (b == 0 && t == 0) rowstart[NE] = E;
}

// ---------------- CSR scatter: segment-sorted packed {r,t} + ev -------------
__global__ void k_scatter(const int* __restrict__ h, const int* __restrict__ r,
                          const int* __restrict__ t, const float* __restrict__ evalv,
                          const int* __restrict__ rowstart, int* __restrict__ cursor,
                          int2* __restrict__ rt_s, float* __restrict__ ev_s, int E) {
    int e = blockIdx.x * blockDim.x + threadIdx.x;
    if (e >= E) return;
    int hi = h[e];
    int pos = atomicAdd(cursor + hi, 1);
    int idx = rowstart[hi] + pos;
    rt_s[idx] = make_int2(r[e], t[e]);
    ev_s[idx] = evalv[e];
}

// ---------------- per-entity aggregation: one wave per entity ---------------
__global__ __launch_bounds__(256) void k_aggregate(const int* __restrict__ rowstart,
                                                   const int2* __restrict__ rt_s,
                                                   const float* __restrict__ ev_s,
                                                   const float* __restrict__ P,
                                                   const unsigned short* __restrict__ Qb,
                                                   const unsigned short* __restrict__ Rb,
                                                   const float* __restrict__ denom,
                                                   const float* __restrict__ bias,
                                                   float* __restrict__ out, int NE) {
    int n = (blockIdx.x * blockDim.x + threadIdx.x) >> 6;
    int lane = threadIdx.x & 63;
    if (n >= NE) return;
    int start = rowstart[n], end = rowstart[n + 1];
    int c0 = lane * 2;
    float2 acc = make_float2(0.f, 0.f);
    for (int i = start; i < end; ++i) {
        int2 rt = rt_s[i];
        float ev = ev_s[i];
        ushort2 q = *(const ushort2*)(Qb + (size_t)rt.y * 128 + c0);
        ushort2 rr = *(const ushort2*)(Rb + (size_t)rt.x * 128 + c0);
        acc.x = fmaf(ev, bf2f(q.x) + bf2f(rr.x), acc.x);
        acc.y = fmaf(ev, bf2f(q.y) + bf2f(rr.y), acc.y);
    }
    float2 bi = *(const float2*)(bias + c0);
    float2 o;
    if (end > start) {
        float inv = 1.f / denom[n];
        float2 p = *(const float2*)(P + (size_t)n * 128 + c0);
        o.x = p.x + acc.x * inv + bi.x;
        o.y = p.y + acc.y * inv + bi.y;
    } else {
        o = bi;
    }
    o.x = fmaxf(o.x, 0.f);
    o.y = fmaxf(o.y, 0.f);
    *(float2*)(out + (size_t)n * 128 + c0) = o;
}

// ============================================================================
static inline size_t align_up(size_t x, size_t a) { return (x + a - 1) / a * a; }

extern "C" void kernel_launch(void* const* d_in, const int* in_sizes, int n_in,
                              void* d_out, int out_size, void* d_ws, size_t ws_size,
                              hipStream_t stream) {
    const int* h_index = (const int*)d_in[0];
    const int* r_index = (const int*)d_in[1];
    const int* t_index = (const int*)d_in[2];
    const float* ent = (const float*)d_in[3];
    const float* rel = (const float*)d_in[4];
    const float* W = (const float*)d_in[5];
    const float* a = (const float*)d_in[6];
    const float* a_b = (const float*)d_in[7];
    const float* bias = (const float*)d_in[8];
    float* out = (float*)d_out;

    int E = in_sizes[0];
    int NE = in_sizes[3] / 128;
    int NR = in_sizes[4] / 128;

    char* p = (char*)d_ws;
    auto alloc = [&](size_t bytes) { char* q = p; p += align_up(bytes, 256); return (void*)q; };
    float* P = (float*)alloc((size_t)NE * 128 * 4);
    unsigned short* Qb = (unsigned short*)alloc((size_t)NE * 128 * 2);
    unsigned short* Rb = (unsigned short*)alloc((size_t)NR * 128 * 2);
    unsigned short* entb = (unsigned short*)alloc((size_t)NE * 128 * 2);
    unsigned short* relb = (unsigned short*)alloc((size_t)NR * 128 * 2);
    unsigned short* Wt = (unsigned short*)alloc((size_t)128 * 384 * 2);
    float* s1 = (float*)alloc((size_t)NE * 4);
    float* s3 = (float*)alloc((size_t)NE * 4);
    float* s2 = (float*)alloc((size_t)NR * 4);
    float* evalv = (float*)alloc((size_t)E * 4);
    float* denom = (float*)alloc((size_t)NE * 4);
    int* count = (int*)alloc((size_t)NE * 4);
    int* cursor = (int*)alloc((size_t)NE * 4);
    int* rowstart = (int*)alloc((size_t)(NE + 1) * 4);
    int NB = (NE + 1023) / 1024;
    int* bsum = (int*)alloc((size_t)NB * 4);
    int2* rt_s = (int2*)alloc((size_t)E * 8);
    float* ev_s = (float*)alloc((size_t)E * 4);
    (void)ws_size; (void)n_in; (void)out_size;

    // 1. casts + W transpose + init
    int n4e = NE * 32, n4r = NR * 32;
    k_cast<<<(n4e + 255) / 256, 256, 0, stream>>>(ent, entb, n4e);
    k_cast<<<(n4r + 255) / 256, 256, 0, stream>>>(rel, relb, n4r);
    k_wt<<<(384 * 128 + 255) / 256, 256, 0, stream>>>(W, Wt);
    k_init<<<(NE + 255) / 256, 256, 0, stream>>>(denom, count, cursor, NE);
    // 2-4. P = ent@W1 (fp32 + s1), Qb = ent@W3 (bf16 + s3), Rb = rel@W2 (bf16 + s2)
    k_mfma_gemm<false><<<(NE + 127) / 128, 256, 0, stream>>>(entb, Wt, 0, P, nullptr, NE, a, s1);
    k_mfma_gemm<true><<<(NE + 127) / 128, 256, 0, stream>>>(entb, Wt, 256, nullptr, Qb, NE, a, s3);
    k_mfma_gemm<true><<<(NR + 127) / 128, 256, 0, stream>>>(relb, Wt, 128, nullptr, Rb, NR, a, s2);
    // 5. per-edge score -> exp -> denom + count
    k_score<<<(E + 255) / 256, 256, 0, stream>>>(h_index, r_index, t_index, s1, s2, s3,
                                                 a_b, evalv, denom, count, E);
    // 6-8. scan -> rowstart
    k_scan_a<<<NB, 256, 0, stream>>>(count, NE, bsum);
    k_scan_b<<<1, 256, 0, stream>>>(bsum, NB);
    k_scan_c<<<NB, 256, 0, stream>>>(count, NE, bsum, rowstart, E);
    // 9. CSR scatter of packed edge data
    k_scatter<<<(E + 255) / 256, 256, 0, stream>>>(h_index, r_index, t_index, evalv,
                                                   rowstart, cursor, rt_s, ev_s, E);
    // 10. aggregate + bias + relu
    k_aggregate<<<(NE + 3) / 4, 256, 0, stream>>>(rowstart, rt_s, ev_s, P, Qb, Rb,
                                                  denom, bias, out, NE);
}

// Round 4
// 248.703 us; speedup vs baseline: 2.0340x; 1.2635x over previous
//
#include <hip/hip_runtime.h>
#include <hip/hip_bf16.h>

#define ALPHA2 0.04f   // leaky(leaky(x)) slope for x<0: 0.2*0.2

typedef __attribute__((ext_vector_type(8))) short short8;
typedef __attribute__((ext_vector_type(4))) float floatx4;

// ---- bf16 helpers (raw round-to-nearest-even; values are finite) ----
__device__ __forceinline__ unsigned short f2bf(float f) {
    unsigned u = __float_as_uint(f);
    unsigned r = (u + 0x7fffu + ((u >> 16) & 1u)) >> 16;
    return (unsigned short)r;
}
__device__ __forceinline__ float bf2f(unsigned short h) {
    return __uint_as_float((unsigned)h << 16);
}

// ---------------- W [384][128] fp32 -> Wt [128][384] bf16 (transposed) ------
__global__ void k_wt(const float* __restrict__ W, unsigned short* __restrict__ Wt) {
    int idx = blockIdx.x * blockDim.x + threadIdx.x;
    if (idx >= 384 * 128) return;
    int k = idx >> 7, n = idx & 127;
    Wt[n * 384 + k] = f2bf(W[idx]);
}

// ---------------- zero count + cursor ----------------
__global__ void k_init(int* __restrict__ count, int* __restrict__ cursor, int NE) {
    int i = blockIdx.x * blockDim.x + threadIdx.x;
    if (i < NE) { count[i] = 0; cursor[i] = 0; }
}

// ---------------- MFMA GEMM phase: 128 rows x 128 cols from staged LDS ------
#define LDA 136  // bf16 row stride in LDS (128 + 8 pad -> conflict-free b128)

__device__ __forceinline__ void gemm_phase(
        const unsigned short* Ash, const unsigned short* Wsh,
        int rowbase, int nrows, int wave, int lane,
        const float* __restrict__ avec,
        unsigned short* __restrict__ OutB, float* __restrict__ svec) {
    int m16 = lane & 15, quad = lane >> 4;
    int rs = wave * 32;

    floatx4 acc[2][8];
    #pragma unroll
    for (int i = 0; i < 2; ++i)
        #pragma unroll
        for (int j = 0; j < 8; ++j) acc[i][j] = (floatx4){0.f, 0.f, 0.f, 0.f};

    #pragma unroll
    for (int kc = 0; kc < 4; ++kc) {
        short8 af[2], bf[8];
        #pragma unroll
        for (int i = 0; i < 2; ++i)
            af[i] = *(const short8*)(Ash + (rs + i * 16 + m16) * LDA + kc * 32 + quad * 8);
        #pragma unroll
        for (int j = 0; j < 8; ++j)
            bf[j] = *(const short8*)(Wsh + (j * 16 + m16) * LDA + kc * 32 + quad * 8);
        #pragma unroll
        for (int i = 0; i < 2; ++i)
            #pragma unroll
            for (int j = 0; j < 8; ++j)
                acc[i][j] = __builtin_amdgcn_mfma_f32_16x16x32_bf16(af[i], bf[j], acc[i][j], 0, 0, 0);
    }

    // epilogue: C/D layout col=lane&15, row=quad*4+reg; fused s = row·avec
    float av[8];
    #pragma unroll
    for (int j = 0; j < 8; ++j) av[j] = avec[j * 16 + m16];
    #pragma unroll
    for (int i = 0; i < 2; ++i) {
        #pragma unroll
        for (int reg = 0; reg < 4; ++reg) {
            int row = rowbase + rs + i * 16 + quad * 4 + reg;
            bool ok = row < nrows;
            float part = 0.f;
            #pragma unroll
            for (int j = 0; j < 8; ++j) {
                float v = acc[i][j][reg];
                part = fmaf(v, av[j], part);
                if (ok) OutB[(size_t)row * 128 + j * 16 + m16] = f2bf(v);
            }
            #pragma unroll
            for (int off = 1; off < 16; off <<= 1) part += __shfl_xor(part, off);
            if (ok && m16 == 0) svec[row] = part;
        }
    }
}

// Reads fp32 A directly (casts to bf16 while staging LDS). Computes one or two
// 128-col outputs (two W slices) from the same staged A tile.
template <bool TWO>
__global__ __launch_bounds__(256) void k_gemm(
        const float* __restrict__ In,            // [nrows][128] fp32
        const unsigned short* __restrict__ Wt,   // [128][384] bf16 (n-major)
        int woffA, unsigned short* __restrict__ OutA, float* __restrict__ svecA,
        int woffB, unsigned short* __restrict__ OutB, float* __restrict__ svecB,
        int nrows, const float* __restrict__ avec) {
    __shared__ unsigned short Ash[128 * LDA];
    __shared__ unsigned short Wsh[128 * LDA];
    int tid = threadIdx.x;
    int rowbase = blockIdx.x * 128;
    int wave = tid >> 6, lane = tid & 63;

    // stage A: 128 rows x 32 chunks of 4 fp32, cast to bf16
    #pragma unroll
    for (int it = 0; it < 16; ++it) {
        int id = it * 256 + tid;            // 0..4095
        int chunk = id & 31, row = id >> 5;
        int grow = rowbase + row;
        if (grow > nrows - 1) grow = nrows - 1;  // clamp: garbage rows masked at store
        float4 v = *(const float4*)(In + (size_t)grow * 128 + chunk * 4);
        ushort4 u = make_ushort4(f2bf(v.x), f2bf(v.y), f2bf(v.z), f2bf(v.w));
        *(ushort4*)(Ash + row * LDA + chunk * 4) = u;
    }
    // stage Wt slice A
    #pragma unroll
    for (int it = 0; it < 8; ++it) {
        int id = it * 256 + tid;
        int chunk = id & 15, n = id >> 4;
        uint4 v = *(const uint4*)(Wt + (size_t)n * 384 + woffA + chunk * 8);
        *(uint4*)(Wsh + n * LDA + chunk * 8) = v;
    }
    __syncthreads();
    gemm_phase(Ash, Wsh, rowbase, nrows, wave, lane, avec, OutA, svecA);

    if (TWO) {
        __syncthreads();  // all phase-1 reads of Wsh done
        #pragma unroll
        for (int it = 0; it < 8; ++it) {
            int id = it * 256 + tid;
            int chunk = id & 15, n = id >> 4;
            uint4 v = *(const uint4*)(Wt + (size_t)n * 384 + woffB + chunk * 8);
            *(uint4*)(Wsh + n * LDA + chunk * 8) = v;
        }
        __syncthreads();
        gemm_phase(Ash, Wsh, rowbase, nrows, wave, lane, avec, OutB, svecB);
    }
}

// ---------------- edge pass 1: degree count only ----------------
__global__ void k_count(const int* __restrict__ h, int* __restrict__ count, int E) {
    int e = blockIdx.x * blockDim.x + threadIdx.x;
    if (e < E) atomicAdd(count + h[e], 1);
}

// ---------------- hierarchical exclusive scan of count -> rowstart ----------
__device__ __forceinline__ int block_incl_scan256(int s, int* sh, int t) {
    sh[t] = s; __syncthreads();
    #pragma unroll
    for (int off = 1; off < 256; off <<= 1) {
        int x = 0;
        if (t >= off) x = sh[t - off];
        __syncthreads();
        sh[t] += x;
        __syncthreads();
    }
    return sh[t];
}

__global__ __launch_bounds__(256) void k_scan_a(const int* __restrict__ count, int NE,
                                                int* __restrict__ bsum) {
    __shared__ int sh[256];
    int b = blockIdx.x, t = threadIdx.x;
    int base = b * 1024 + t * 4, s = 0;
    #pragma unroll
    for (int j = 0; j < 4; ++j) { int i = base + j; if (i < NE) s += count[i]; }
    sh[t] = s; __syncthreads();
    for (int off = 128; off > 0; off >>= 1) {
        if (t < off) sh[t] += sh[t + off];
        __syncthreads();
    }
    if (t == 0) bsum[b] = sh[0];
}

__global__ __launch_bounds__(256) void k_scan_b(int* __restrict__ bsum, int NB) {
    __shared__ int sh[256];
    int t = threadIdx.x;
    int v[4]; int s = 0;
    #pragma unroll
    for (int j = 0; j < 4; ++j) { int i = t * 4 + j; v[j] = (i < NB) ? bsum[i] : 0; s += v[j]; }
    int incl = block_incl_scan256(s, sh, t);
    int excl = incl - s;
    #pragma unroll
    for (int j = 0; j < 4; ++j) {
        int i = t * 4 + j;
        if (i < NB) { int tmp = v[j]; bsum[i] = excl; excl += tmp; }
    }
}

__global__ __launch_bounds__(256) void k_scan_c(const int* __restrict__ count, int NE,
                                                const int* __restrict__ bsum,
                                                int* __restrict__ rowstart, int E) {
    __shared__ int sh[256];
    int b = blockIdx.x, t = threadIdx.x;
    int base = b * 1024 + t * 4;
    int v[4]; int s = 0;
    #pragma unroll
    for (int j = 0; j < 4; ++j) { int i = base + j; v[j] = (i < NE) ? count[i] : 0; s += v[j]; }
    int incl = block_incl_scan256(s, sh, t);
    int excl = bsum[b] + incl - s;
    #pragma unroll
    for (int j = 0; j < 4; ++j) {
        int i = base + j;
        if (i < NE) { rowstart[i] = excl; excl += v[j]; }
    }
    if (b == 0 && t == 0) rowstart[NE] = E;
}

// ---------------- edge pass 2: score -> exp -> CSR scatter {r,t,ev} --------
// (no max shift: |score| <~ 6 so exp is safe in fp32; softmax shift-invariant)
__global__ void k_score_scatter(const int* __restrict__ h, const int* __restrict__ r,
                                const int* __restrict__ t, const float* __restrict__ s1,
                                const float* __restrict__ s2, const float* __restrict__ s3,
                                const float* __restrict__ a_b,
                                const int* __restrict__ rowstart, int* __restrict__ cursor,
                                uint4* __restrict__ rt_s, int E) {
    int e = blockIdx.x * blockDim.x + threadIdx.x;
    if (e >= E) return;
    int hi = h[e], ri = r[e], ti = t[e];
    float x = s1[hi] + s2[ri] + s3[ti] + a_b[0];
    float sc = (x >= 0.f) ? x : ALPHA2 * x;
    float ev = __expf(sc);
    int pos = atomicAdd(cursor + hi, 1);
    rt_s[rowstart[hi] + pos] = make_uint4((unsigned)ri, (unsigned)ti, __float_as_uint(ev), 0u);
}

// ---------------- per-entity aggregation: one wave per entity ---------------
// denom = sum of ev computed in-wave (broadcast loads are free) - no atomics.
__global__ __launch_bounds__(256) void k_aggregate(const int* __restrict__ rowstart,
                                                   const uint4* __restrict__ rt_s,
                                                   const unsigned short* __restrict__ Pb,
                                                   const unsigned short* __restrict__ Qb,
                                                   const unsigned short* __restrict__ Rb,
                                                   const float* __restrict__ bias,
                                                   float* __restrict__ out, int NE) {
    int n = (blockIdx.x * blockDim.x + threadIdx.x) >> 6;
    int lane = threadIdx.x & 63;
    if (n >= NE) return;
    int start = rowstart[n], end = rowstart[n + 1];
    int c0 = lane * 2;
    float2 acc = make_float2(0.f, 0.f);
    float evsum = 0.f;
    int i = start;
    for (; i + 2 <= end; i += 2) {
        uint4 m0 = rt_s[i], m1 = rt_s[i + 1];
        float ev0 = __uint_as_float(m0.z), ev1 = __uint_as_float(m1.z);
        ushort2 q0 = *(const ushort2*)(Qb + (size_t)m0.y * 128 + c0);
        ushort2 r0 = *(const ushort2*)(Rb + (size_t)m0.x * 128 + c0);
        ushort2 q1 = *(const ushort2*)(Qb + (size_t)m1.y * 128 + c0);
        ushort2 r1 = *(const ushort2*)(Rb + (size_t)m1.x * 128 + c0);
        evsum += ev0 + ev1;
        acc.x = fmaf(ev0, bf2f(q0.x) + bf2f(r0.x), acc.x);
        acc.y = fmaf(ev0, bf2f(q0.y) + bf2f(r0.y), acc.y);
        acc.x = fmaf(ev1, bf2f(q1.x) + bf2f(r1.x), acc.x);
        acc.y = fmaf(ev1, bf2f(q1.y) + bf2f(r1.y), acc.y);
    }
    if (i < end) {
        uint4 m0 = rt_s[i];
        float ev0 = __uint_as_float(m0.z);
        ushort2 q0 = *(const ushort2*)(Qb + (size_t)m0.y * 128 + c0);
        ushort2 r0 = *(const ushort2*)(Rb + (size_t)m0.x * 128 + c0);
        evsum += ev0;
        acc.x = fmaf(ev0, bf2f(q0.x) + bf2f(r0.x), acc.x);
        acc.y = fmaf(ev0, bf2f(q0.y) + bf2f(r0.y), acc.y);
    }
    float2 bi = *(const float2*)(bias + c0);
    float2 o;
    if (end > start) {
        float inv = 1.f / evsum;
        ushort2 pb = *(const ushort2*)(Pb + (size_t)n * 128 + c0);
        o.x = bf2f(pb.x) + acc.x * inv + bi.x;
        o.y = bf2f(pb.y) + acc.y * inv + bi.y;
    } else {
        o = bi;
    }
    o.x = fmaxf(o.x, 0.f);
    o.y = fmaxf(o.y, 0.f);
    *(float2*)(out + (size_t)n * 128 + c0) = o;
}

// ============================================================================
static inline size_t align_up(size_t x, size_t a) { return (x + a - 1) / a * a; }

extern "C" void kernel_launch(void* const* d_in, const int* in_sizes, int n_in,
                              void* d_out, int out_size, void* d_ws, size_t ws_size,
                              hipStream_t stream) {
    const int* h_index = (const int*)d_in[0];
    const int* r_index = (const int*)d_in[1];
    const int* t_index = (const int*)d_in[2];
    const float* ent = (const float*)d_in[3];
    const float* rel = (const float*)d_in[4];
    const float* W = (const float*)d_in[5];
    const float* a = (const float*)d_in[6];
    const float* a_b = (const float*)d_in[7];
    const float* bias = (const float*)d_in[8];
    float* out = (float*)d_out;

    int E = in_sizes[0];
    int NE = in_sizes[3] / 128;
    int NR = in_sizes[4] / 128;

    char* p = (char*)d_ws;
    auto alloc = [&](size_t bytes) { char* q = p; p += align_up(bytes, 256); return (void*)q; };
    unsigned short* Pb = (unsigned short*)alloc((size_t)NE * 128 * 2);
    unsigned short* Qb = (unsigned short*)alloc((size_t)NE * 128 * 2);
    unsigned short* Rb = (unsigned short*)alloc((size_t)NR * 128 * 2);
    unsigned short* Wt = (unsigned short*)alloc((size_t)128 * 384 * 2);
    float* s1 = (float*)alloc((size_t)NE * 4);
    float* s3 = (float*)alloc((size_t)NE * 4);
    float* s2 = (float*)alloc((size_t)NR * 4);
    int* count = (int*)alloc((size_t)NE * 4);
    int* cursor = (int*)alloc((size_t)NE * 4);
    int* rowstart = (int*)alloc((size_t)(NE + 1) * 4);
    int NB = (NE + 1023) / 1024;
    int* bsum = (int*)alloc((size_t)NB * 4);
    uint4* rt_s = (uint4*)alloc((size_t)E * 16);
    (void)ws_size; (void)n_in; (void)out_size;

    // 1. W transpose/cast + zero atomics
    k_wt<<<(384 * 128 + 255) / 256, 256, 0, stream>>>(W, Wt);
    k_init<<<(NE + 255) / 256, 256, 0, stream>>>(count, cursor, NE);
    // 2. edge pass 1: degree count (independent of GEMMs)
    k_count<<<(E + 255) / 256, 256, 0, stream>>>(h_index, count, E);
    // 3. Pb = ent@W1 (+s1) and Qb = ent@W3 (+s3) from one A-stage
    k_gemm<true><<<(NE + 127) / 128, 256, 0, stream>>>(ent, Wt, 0, Pb, s1, 256, Qb, s3, NE, a);
    // 4. Rb = rel@W2 (+s2)
    k_gemm<false><<<(NR + 127) / 128, 256, 0, stream>>>(rel, Wt, 128, Rb, s2, 0, nullptr, nullptr, NR, a);
    // 5-7. scan -> rowstart
    k_scan_a<<<NB, 256, 0, stream>>>(count, NE, bsum);
    k_scan_b<<<1, 256, 0, stream>>>(bsum, NB);
    k_scan_c<<<NB, 256, 0, stream>>>(count, NE, bsum, rowstart, E);
    // 8. edge pass 2: score -> exp -> CSR scatter
    k_score_scatter<<<(E + 255) / 256, 256, 0, stream>>>(h_index, r_index, t_index,
                                                         s1, s2, s3, a_b, rowstart,
                                                         cursor, rt_s, E);
    // 9. aggregate + bias + relu (denom computed in-wave)
    k_aggregate<<<(NE + 3) / 4, 256, 0, stream>>>(rowstart, rt_s, Pb, Qb, Rb, bias, out, NE);
}

// Round 5
// 230.846 us; speedup vs baseline: 2.1914x; 1.0774x over previous
//
#include <hip/hip_runtime.h>
#include <hip/hip_bf16.h>

#define ALPHA2 0.04f   // leaky(leaky(x)) slope for x<0: 0.2*0.2

typedef __attribute__((ext_vector_type(8))) short short8;
typedef __attribute__((ext_vector_type(4))) float floatx4;
typedef __attribute__((ext_vector_type(8))) unsigned short ushort8;

// ---- bf16 helpers (raw round-to-nearest-even; values are finite) ----
__device__ __forceinline__ unsigned short f2bf(float f) {
    unsigned u = __float_as_uint(f);
    unsigned r = (u + 0x7fffu + ((u >> 16) & 1u)) >> 16;
    return (unsigned short)r;
}
__device__ __forceinline__ float bf2f(unsigned short h) {
    return __uint_as_float((unsigned)h << 16);
}

// ---------------- prep: Wt transpose/cast + zero count/cursor ----------------
__global__ void k_prep(const float* __restrict__ W, unsigned short* __restrict__ Wt,
                       int* __restrict__ count, int* __restrict__ cursor, int NE) {
    int idx = blockIdx.x * blockDim.x + threadIdx.x;
    if (idx < 384 * 128) {
        int k = idx >> 7, n = idx & 127;
        Wt[n * 384 + k] = f2bf(W[idx]);
    }
    if (idx < NE) { count[idx] = 0; cursor[idx] = 0; }
}

// ---------------- MFMA GEMM phase: 128 rows x 128 cols from staged LDS ------
#define LDA 136  // bf16 row stride in LDS (128 + 8 pad -> conflict-free b128)

__device__ __forceinline__ void gemm_phase(
        const unsigned short* Ash, const unsigned short* Wsh,
        int rowbase, int nrows, int wave, int lane,
        const float* __restrict__ avec,
        unsigned short* __restrict__ OutB, float* __restrict__ svec) {
    int m16 = lane & 15, quad = lane >> 4;
    int rs = wave * 32;

    floatx4 acc[2][8];
    #pragma unroll
    for (int i = 0; i < 2; ++i)
        #pragma unroll
        for (int j = 0; j < 8; ++j) acc[i][j] = (floatx4){0.f, 0.f, 0.f, 0.f};

    #pragma unroll
    for (int kc = 0; kc < 4; ++kc) {
        short8 af[2], bf[8];
        #pragma unroll
        for (int i = 0; i < 2; ++i)
            af[i] = *(const short8*)(Ash + (rs + i * 16 + m16) * LDA + kc * 32 + quad * 8);
        #pragma unroll
        for (int j = 0; j < 8; ++j)
            bf[j] = *(const short8*)(Wsh + (j * 16 + m16) * LDA + kc * 32 + quad * 8);
        #pragma unroll
        for (int i = 0; i < 2; ++i)
            #pragma unroll
            for (int j = 0; j < 8; ++j)
                acc[i][j] = __builtin_amdgcn_mfma_f32_16x16x32_bf16(af[i], bf[j], acc[i][j], 0, 0, 0);
    }

    // epilogue: C/D layout col=lane&15, row=quad*4+reg; fused s = row·avec
    float av[8];
    #pragma unroll
    for (int j = 0; j < 8; ++j) av[j] = avec[j * 16 + m16];
    #pragma unroll
    for (int i = 0; i < 2; ++i) {
        #pragma unroll
        for (int reg = 0; reg < 4; ++reg) {
            int row = rowbase + rs + i * 16 + quad * 4 + reg;
            bool ok = row < nrows;
            float part = 0.f;
            #pragma unroll
            for (int j = 0; j < 8; ++j) {
                float v = acc[i][j][reg];
                part = fmaf(v, av[j], part);
                if (ok) OutB[(size_t)row * 128 + j * 16 + m16] = f2bf(v);
            }
            #pragma unroll
            for (int off = 1; off < 16; off <<= 1) part += __shfl_xor(part, off);
            if (ok && m16 == 0) svec[row] = part;
        }
    }
}

// Reads fp32 A directly (casts to bf16 while staging LDS). Computes one or two
// 128-col outputs (two W slices) from the same staged A tile.
template <bool TWO>
__global__ __launch_bounds__(256) void k_gemm(
        const float* __restrict__ In,            // [nrows][128] fp32
        const unsigned short* __restrict__ Wt,   // [128][384] bf16 (n-major)
        int woffA, unsigned short* __restrict__ OutA, float* __restrict__ svecA,
        int woffB, unsigned short* __restrict__ OutB, float* __restrict__ svecB,
        int nrows, const float* __restrict__ avec) {
    __shared__ unsigned short Ash[128 * LDA];
    __shared__ unsigned short Wsh[128 * LDA];
    int tid = threadIdx.x;
    int rowbase = blockIdx.x * 128;
    int wave = tid >> 6, lane = tid & 63;

    // stage A: 128 rows x 32 chunks of 4 fp32, cast to bf16
    #pragma unroll
    for (int it = 0; it < 16; ++it) {
        int id = it * 256 + tid;            // 0..4095
        int chunk = id & 31, row = id >> 5;
        int grow = rowbase + row;
        if (grow > nrows - 1) grow = nrows - 1;  // clamp: garbage rows masked at store
        float4 v = *(const float4*)(In + (size_t)grow * 128 + chunk * 4);
        ushort4 u = make_ushort4(f2bf(v.x), f2bf(v.y), f2bf(v.z), f2bf(v.w));
        *(ushort4*)(Ash + row * LDA + chunk * 4) = u;
    }
    // stage Wt slice A
    #pragma unroll
    for (int it = 0; it < 8; ++it) {
        int id = it * 256 + tid;
        int chunk = id & 15, n = id >> 4;
        uint4 v = *(const uint4*)(Wt + (size_t)n * 384 + woffA + chunk * 8);
        *(uint4*)(Wsh + n * LDA + chunk * 8) = v;
    }
    __syncthreads();
    gemm_phase(Ash, Wsh, rowbase, nrows, wave, lane, avec, OutA, svecA);

    if (TWO) {
        __syncthreads();  // all phase-1 reads of Wsh done
        #pragma unroll
        for (int it = 0; it < 8; ++it) {
            int id = it * 256 + tid;
            int chunk = id & 15, n = id >> 4;
            uint4 v = *(const uint4*)(Wt + (size_t)n * 384 + woffB + chunk * 8);
            *(uint4*)(Wsh + n * LDA + chunk * 8) = v;
        }
        __syncthreads();
        gemm_phase(Ash, Wsh, rowbase, nrows, wave, lane, avec, OutB, svecB);
    }
}

// ---------------- edge pass 1: degree count only ----------------
__global__ void k_count(const int* __restrict__ h, int* __restrict__ count, int E) {
    int e = blockIdx.x * blockDim.x + threadIdx.x;
    if (e < E) atomicAdd(count + h[e], 1);
}

// ---------------- hierarchical exclusive scan of count -> rowstart ----------
__device__ __forceinline__ int block_incl_scan256(int s, int* sh, int t) {
    sh[t] = s; __syncthreads();
    #pragma unroll
    for (int off = 1; off < 256; off <<= 1) {
        int x = 0;
        if (t >= off) x = sh[t - off];
        __syncthreads();
        sh[t] += x;
        __syncthreads();
    }
    return sh[t];
}

__global__ __launch_bounds__(256) void k_scan_a(const int* __restrict__ count, int NE,
                                                int* __restrict__ bsum) {
    __shared__ int sh[256];
    int b = blockIdx.x, t = threadIdx.x;
    int base = b * 1024 + t * 4, s = 0;
    #pragma unroll
    for (int j = 0; j < 4; ++j) { int i = base + j; if (i < NE) s += count[i]; }
    sh[t] = s; __syncthreads();
    for (int off = 128; off > 0; off >>= 1) {
        if (t < off) sh[t] += sh[t + off];
        __syncthreads();
    }
    if (t == 0) bsum[b] = sh[0];
}

__global__ __launch_bounds__(256) void k_scan_b(int* __restrict__ bsum, int NB) {
    __shared__ int sh[256];
    int t = threadIdx.x;
    int v[4]; int s = 0;
    #pragma unroll
    for (int j = 0; j < 4; ++j) { int i = t * 4 + j; v[j] = (i < NB) ? bsum[i] : 0; s += v[j]; }
    int incl = block_incl_scan256(s, sh, t);
    int excl = incl - s;
    #pragma unroll
    for (int j = 0; j < 4; ++j) {
        int i = t * 4 + j;
        if (i < NB) { int tmp = v[j]; bsum[i] = excl; excl += tmp; }
    }
}

__global__ __launch_bounds__(256) void k_scan_c(const int* __restrict__ count, int NE,
                                                const int* __restrict__ bsum,
                                                int* __restrict__ rowstart, int E) {
    __shared__ int sh[256];
    int b = blockIdx.x, t = threadIdx.x;
    int base = b * 1024 + t * 4;
    int v[4]; int s = 0;
    #pragma unroll
    for (int j = 0; j < 4; ++j) { int i = base + j; v[j] = (i < NE) ? count[i] : 0; s += v[j]; }
    int incl = block_incl_scan256(s, sh, t);
    int excl = bsum[b] + incl - s;
    #pragma unroll
    for (int j = 0; j < 4; ++j) {
        int i = base + j;
        if (i < NE) { rowstart[i] = excl; excl += v[j]; }
    }
    if (b == 0 && t == 0) rowstart[NE] = E;
}

// ---------------- edge pass 2: score -> exp -> CSR scatter {(r<<17)|t, ev} --
// (no max shift: |score| <~ 6 so exp is safe in fp32; softmax shift-invariant)
// t < 2^17 (NE=100k), r < 2^10 (NR=1000) -> pack into 32 bits.
__global__ void k_score_scatter(const int* __restrict__ h, const int* __restrict__ r,
                                const int* __restrict__ t, const float* __restrict__ s1,
                                const float* __restrict__ s2, const float* __restrict__ s3,
                                const float* __restrict__ a_b,
                                const int* __restrict__ rowstart, int* __restrict__ cursor,
                                uint2* __restrict__ rt_s, int E) {
    int e = blockIdx.x * blockDim.x + threadIdx.x;
    if (e >= E) return;
    int hi = h[e], ri = r[e], ti = t[e];
    float x = s1[hi] + s2[ri] + s3[ti] + a_b[0];
    float sc = (x >= 0.f) ? x : ALPHA2 * x;
    float ev = __expf(sc);
    int pos = atomicAdd(cursor + hi, 1);
    rt_s[rowstart[hi] + pos] = make_uint2(((unsigned)ri << 17) | (unsigned)ti,
                                          __float_as_uint(ev));
}

// ---------------- per-entity aggregation: 16 lanes per entity ---------------
// 4 entities per wave -> 4x gather-level parallelism; 16B loads per lane.
// denom = sum of ev computed in-lane (broadcast loads) - no atomics.
__global__ __launch_bounds__(256) void k_aggregate(const int* __restrict__ rowstart,
                                                   const uint2* __restrict__ rt_s,
                                                   const unsigned short* __restrict__ Pb,
                                                   const unsigned short* __restrict__ Qb,
                                                   const unsigned short* __restrict__ Rb,
                                                   const float* __restrict__ bias,
                                                   float* __restrict__ out, int NE) {
    int gid = blockIdx.x * blockDim.x + threadIdx.x;
    int n = gid >> 4;        // entity
    int sl = gid & 15;       // sublane: covers 8 of 128 cols
    if (n >= NE) return;
    int start = rowstart[n], end = rowstart[n + 1];
    int c0 = sl * 8;
    float acc[8] = {};
    float evsum = 0.f;
    int i = start;
    for (; i + 2 <= end; i += 2) {
        uint2 m0 = rt_s[i], m1 = rt_s[i + 1];
        float ev0 = __uint_as_float(m0.y), ev1 = __uint_as_float(m1.y);
        unsigned t0 = m0.x & 0x1FFFFu, r0 = m0.x >> 17;
        unsigned t1 = m1.x & 0x1FFFFu, r1 = m1.x >> 17;
        ushort8 q0 = *(const ushort8*)(Qb + (size_t)t0 * 128 + c0);
        ushort8 rr0 = *(const ushort8*)(Rb + (size_t)r0 * 128 + c0);
        ushort8 q1 = *(const ushort8*)(Qb + (size_t)t1 * 128 + c0);
        ushort8 rr1 = *(const ushort8*)(Rb + (size_t)r1 * 128 + c0);
        evsum += ev0 + ev1;
        #pragma unroll
        for (int j = 0; j < 8; ++j)
            acc[j] = fmaf(ev0, bf2f(q0[j]) + bf2f(rr0[j]), acc[j]);
        #pragma unroll
        for (int j = 0; j < 8; ++j)
            acc[j] = fmaf(ev1, bf2f(q1[j]) + bf2f(rr1[j]), acc[j]);
    }
    if (i < end) {
        uint2 m0 = rt_s[i];
        float ev0 = __uint_as_float(m0.y);
        unsigned t0 = m0.x & 0x1FFFFu, r0 = m0.x >> 17;
        ushort8 q0 = *(const ushort8*)(Qb + (size_t)t0 * 128 + c0);
        ushort8 rr0 = *(const ushort8*)(Rb + (size_t)r0 * 128 + c0);
        evsum += ev0;
        #pragma unroll
        for (int j = 0; j < 8; ++j)
            acc[j] = fmaf(ev0, bf2f(q0[j]) + bf2f(rr0[j]), acc[j]);
    }
    float4 b0 = *(const float4*)(bias + c0);
    float4 b1 = *(const float4*)(bias + c0 + 4);
    float bi[8] = {b0.x, b0.y, b0.z, b0.w, b1.x, b1.y, b1.z, b1.w};
    float o[8];
    if (end > start) {
        float inv = 1.f / evsum;
        ushort8 pb = *(const ushort8*)(Pb + (size_t)n * 128 + c0);
        #pragma unroll
        for (int j = 0; j < 8; ++j) o[j] = bf2f(pb[j]) + acc[j] * inv + bi[j];
    } else {
        #pragma unroll
        for (int j = 0; j < 8; ++j) o[j] = bi[j];
    }
    #pragma unroll
    for (int j = 0; j < 8; ++j) o[j] = fmaxf(o[j], 0.f);
    float* op = out + (size_t)n * 128 + c0;
    *(float4*)(op)     = make_float4(o[0], o[1], o[2], o[3]);
    *(float4*)(op + 4) = make_float4(o[4], o[5], o[6], o[7]);
}

// ============================================================================
static inline size_t align_up(size_t x, size_t a) { return (x + a - 1) / a * a; }

extern "C" void kernel_launch(void* const* d_in, const int* in_sizes, int n_in,
                              void* d_out, int out_size, void* d_ws, size_t ws_size,
                              hipStream_t stream) {
    const int* h_index = (const int*)d_in[0];
    const int* r_index = (const int*)d_in[1];
    const int* t_index = (const int*)d_in[2];
    const float* ent = (const float*)d_in[3];
    const float* rel = (const float*)d_in[4];
    const float* W = (const float*)d_in[5];
    const float* a = (const float*)d_in[6];
    const float* a_b = (const float*)d_in[7];
    const float* bias = (const float*)d_in[8];
    float* out = (float*)d_out;

    int E = in_sizes[0];
    int NE = in_sizes[3] / 128;
    int NR = in_sizes[4] / 128;

    char* p = (char*)d_ws;
    auto alloc = [&](size_t bytes) { char* q = p; p += align_up(bytes, 256); return (void*)q; };
    unsigned short* Pb = (unsigned short*)alloc((size_t)NE * 128 * 2);
    unsigned short* Qb = (unsigned short*)alloc((size_t)NE * 128 * 2);
    unsigned short* Rb = (unsigned short*)alloc((size_t)NR * 128 * 2);
    unsigned short* Wt = (unsigned short*)alloc((size_t)128 * 384 * 2);
    float* s1 = (float*)alloc((size_t)NE * 4);
    float* s3 = (float*)alloc((size_t)NE * 4);
    float* s2 = (float*)alloc((size_t)NR * 4);
    int* count = (int*)alloc((size_t)NE * 4);
    int* cursor = (int*)alloc((size_t)NE * 4);
    int* rowstart = (int*)alloc((size_t)(NE + 1) * 4);
    int NB = (NE + 1023) / 1024;
    int* bsum = (int*)alloc((size_t)NB * 4);
    uint2* rt_s = (uint2*)alloc((size_t)E * 8);
    (void)ws_size; (void)n_in; (void)out_size;

    // 1. prep: W transpose/cast + zero atomics
    int nprep = (NE > 384 * 128) ? NE : 384 * 128;
    k_prep<<<(nprep + 255) / 256, 256, 0, stream>>>(W, Wt, count, cursor, NE);
    // 2. edge pass 1: degree count (independent of GEMMs)
    k_count<<<(E + 255) / 256, 256, 0, stream>>>(h_index, count, E);
    // 3. Pb = ent@W1 (+s1) and Qb = ent@W3 (+s3) from one A-stage
    k_gemm<true><<<(NE + 127) / 128, 256, 0, stream>>>(ent, Wt, 0, Pb, s1, 256, Qb, s3, NE, a);
    // 4. Rb = rel@W2 (+s2)
    k_gemm<false><<<(NR + 127) / 128, 256, 0, stream>>>(rel, Wt, 128, Rb, s2, 0, nullptr, nullptr, NR, a);
    // 5-7. scan -> rowstart
    k_scan_a<<<NB, 256, 0, stream>>>(count, NE, bsum);
    k_scan_b<<<1, 256, 0, stream>>>(bsum, NB);
    k_scan_c<<<NB, 256, 0, stream>>>(count, NE, bsum, rowstart, E);
    // 8. edge pass 2: score -> exp -> CSR scatter (packed 8B records)
    k_score_scatter<<<(E + 255) / 256, 256, 0, stream>>>(h_index, r_index, t_index,
                                                         s1, s2, s3, a_b, rowstart,
                                                         cursor, rt_s, E);
    // 9. aggregate + bias + relu (16 lanes/entity, denom in-register)
    k_aggregate<<<(NE * 16 + 255) / 256, 256, 0, stream>>>(rowstart, rt_s, Pb, Qb, Rb,
                                                           bias, out, NE);
}

// Round 6
// 216.467 us; speedup vs baseline: 2.3370x; 1.0664x over previous
//
#include <hip/hip_runtime.h>
#include <hip/hip_bf16.h>

#define ALPHA2 0.04f   // leaky(leaky(x)) slope for x<0: 0.2*0.2

typedef __attribute__((ext_vector_type(8))) short short8;
typedef __attribute__((ext_vector_type(4))) float floatx4;
typedef __attribute__((ext_vector_type(8))) unsigned short ushort8;

// ---- bf16 helpers (raw round-to-nearest-even; values are finite) ----
__device__ __forceinline__ unsigned short f2bf(float f) {
    unsigned u = __float_as_uint(f);
    unsigned r = (u + 0x7fffu + ((u >> 16) & 1u)) >> 16;
    return (unsigned short)r;
}
__device__ __forceinline__ float bf2f(unsigned short h) {
    return __uint_as_float((unsigned)h << 16);
}

// ---------------- prep: Wt transpose/cast + zero count ----------------
__global__ void k_prep(const float* __restrict__ W, unsigned short* __restrict__ Wt,
                       int* __restrict__ count, int NE) {
    int idx = blockIdx.x * blockDim.x + threadIdx.x;
    if (idx < 384 * 128) {
        int k = idx >> 7, n = idx & 127;
        Wt[n * 384 + k] = f2bf(W[idx]);
    }
    if (idx < NE) count[idx] = 0;
}

// ---------------- MFMA GEMM phase: 128 rows x 128 cols from staged LDS ------
#define LDA 136  // bf16 row stride in LDS (128 + 8 pad -> conflict-free b128)

// Computes C = Ash @ Wsh^T(slice), fused svec[row] = C_row · avec, then
// round-trips C through Wsh (bf16) to emit fully-coalesced 16B global stores.
__device__ __forceinline__ void gemm_phase(
        const unsigned short* Ash, unsigned short* Wsh,
        int rowbase, int nrows, int wave, int lane, int tid,
        const float* __restrict__ avec,
        unsigned short* __restrict__ OutB, float* __restrict__ svec) {
    int m16 = lane & 15, quad = lane >> 4;
    int rs = wave * 32;

    floatx4 acc[2][8];
    #pragma unroll
    for (int i = 0; i < 2; ++i)
        #pragma unroll
        for (int j = 0; j < 8; ++j) acc[i][j] = (floatx4){0.f, 0.f, 0.f, 0.f};

    #pragma unroll
    for (int kc = 0; kc < 4; ++kc) {
        short8 af[2], bf[8];
        #pragma unroll
        for (int i = 0; i < 2; ++i)
            af[i] = *(const short8*)(Ash + (rs + i * 16 + m16) * LDA + kc * 32 + quad * 8);
        #pragma unroll
        for (int j = 0; j < 8; ++j)
            bf[j] = *(const short8*)(Wsh + (j * 16 + m16) * LDA + kc * 32 + quad * 8);
        #pragma unroll
        for (int i = 0; i < 2; ++i)
            #pragma unroll
            for (int j = 0; j < 8; ++j)
                acc[i][j] = __builtin_amdgcn_mfma_f32_16x16x32_bf16(af[i], bf[j], acc[i][j], 0, 0, 0);
    }

    // fused s = row·avec from registers (C/D layout: col=lane&15, row=quad*4+reg)
    float av[8];
    #pragma unroll
    for (int j = 0; j < 8; ++j) av[j] = avec[j * 16 + m16];
    #pragma unroll
    for (int i = 0; i < 2; ++i) {
        #pragma unroll
        for (int reg = 0; reg < 4; ++reg) {
            int row = rowbase + rs + i * 16 + quad * 4 + reg;
            float part = 0.f;
            #pragma unroll
            for (int j = 0; j < 8; ++j) part = fmaf(acc[i][j][reg], av[j], part);
            #pragma unroll
            for (int off = 1; off < 16; off <<= 1) part += __shfl_xor(part, off);
            if (row < nrows && m16 == 0) svec[row] = part;
        }
    }

    __syncthreads();  // all MFMA reads of Wsh done -> safe to overwrite with C
    #pragma unroll
    for (int i = 0; i < 2; ++i)
        #pragma unroll
        for (int reg = 0; reg < 4; ++reg) {
            int lrow = rs + i * 16 + quad * 4 + reg;
            #pragma unroll
            for (int j = 0; j < 8; ++j)
                Wsh[lrow * LDA + j * 16 + m16] = f2bf(acc[i][j][reg]);
        }
    __syncthreads();
    // coalesced readout: 128 rows x 16 chunks of 8 bf16 (16B per lane)
    #pragma unroll
    for (int it = 0; it < 8; ++it) {
        int id = it * 256 + tid;            // 0..2047
        int chunk = id & 15, row = id >> 4;
        int grow = rowbase + row;
        if (grow < nrows) {
            ushort8 v = *(const ushort8*)(Wsh + row * LDA + chunk * 8);
            *(ushort8*)(OutB + (size_t)grow * 128 + chunk * 8) = v;
        }
    }
}

// Reads fp32 A directly (casts to bf16 while staging LDS). Computes one or two
// 128-col outputs (two W slices) from the same staged A tile.
template <bool TWO>
__global__ __launch_bounds__(256) void k_gemm(
        const float* __restrict__ In,            // [nrows][128] fp32
        const unsigned short* __restrict__ Wt,   // [128][384] bf16 (n-major)
        int woffA, unsigned short* __restrict__ OutA, float* __restrict__ svecA,
        int woffB, unsigned short* __restrict__ OutB, float* __restrict__ svecB,
        int nrows, const float* __restrict__ avec) {
    __shared__ unsigned short Ash[128 * LDA];
    __shared__ unsigned short Wsh[128 * LDA];
    int tid = threadIdx.x;
    int rowbase = blockIdx.x * 128;
    int wave = tid >> 6, lane = tid & 63;

    // stage A: 128 rows x 32 chunks of 4 fp32, cast to bf16
    #pragma unroll
    for (int it = 0; it < 16; ++it) {
        int id = it * 256 + tid;            // 0..4095
        int chunk = id & 31, row = id >> 5;
        int grow = rowbase + row;
        if (grow > nrows - 1) grow = nrows - 1;  // clamp: garbage rows masked at store
        float4 v = *(const float4*)(In + (size_t)grow * 128 + chunk * 4);
        ushort4 u = make_ushort4(f2bf(v.x), f2bf(v.y), f2bf(v.z), f2bf(v.w));
        *(ushort4*)(Ash + row * LDA + chunk * 4) = u;
    }
    // stage Wt slice A
    #pragma unroll
    for (int it = 0; it < 8; ++it) {
        int id = it * 256 + tid;
        int chunk = id & 15, n = id >> 4;
        uint4 v = *(const uint4*)(Wt + (size_t)n * 384 + woffA + chunk * 8);
        *(uint4*)(Wsh + n * LDA + chunk * 8) = v;
    }
    __syncthreads();
    gemm_phase(Ash, Wsh, rowbase, nrows, wave, lane, tid, avec, OutA, svecA);

    if (TWO) {
        __syncthreads();  // all phase-1 readout of Wsh done
        #pragma unroll
        for (int it = 0; it < 8; ++it) {
            int id = it * 256 + tid;
            int chunk = id & 15, n = id >> 4;
            uint4 v = *(const uint4*)(Wt + (size_t)n * 384 + woffB + chunk * 8);
            *(uint4*)(Wsh + n * LDA + chunk * 8) = v;
        }
        __syncthreads();
        gemm_phase(Ash, Wsh, rowbase, nrows, wave, lane, tid, avec, OutB, svecB);
    }
}

// ---------------- edge pass 1: degree count + per-edge rank ----------------
// rank[e] = position of edge e within its segment (arrival order).
__global__ void k_count(const int* __restrict__ h, int* __restrict__ count,
                        int* __restrict__ rank, int E) {
    int e = blockIdx.x * blockDim.x + threadIdx.x;
    if (e < E) rank[e] = atomicAdd(count + h[e], 1);
}

// ---------------- hierarchical exclusive scan of count -> rowstart ----------
__device__ __forceinline__ int block_incl_scan256(int s, int* sh, int t) {
    sh[t] = s; __syncthreads();
    #pragma unroll
    for (int off = 1; off < 256; off <<= 1) {
        int x = 0;
        if (t >= off) x = sh[t - off];
        __syncthreads();
        sh[t] += x;
        __syncthreads();
    }
    return sh[t];
}

__global__ __launch_bounds__(256) void k_scan_a(const int* __restrict__ count, int NE,
                                                int* __restrict__ bsum) {
    __shared__ int sh[256];
    int b = blockIdx.x, t = threadIdx.x;
    int base = b * 1024 + t * 4, s = 0;
    #pragma unroll
    for (int j = 0; j < 4; ++j) { int i = base + j; if (i < NE) s += count[i]; }
    sh[t] = s; __syncthreads();
    for (int off = 128; off > 0; off >>= 1) {
        if (t < off) sh[t] += sh[t + off];
        __syncthreads();
    }
    if (t == 0) bsum[b] = sh[0];
}

__global__ __launch_bounds__(256) void k_scan_b(int* __restrict__ bsum, int NB) {
    __shared__ int sh[256];
    int t = threadIdx.x;
    int v[4]; int s = 0;
    #pragma unroll
    for (int j = 0; j < 4; ++j) { int i = t * 4 + j; v[j] = (i < NB) ? bsum[i] : 0; s += v[j]; }
    int incl = block_incl_scan256(s, sh, t);
    int excl = incl - s;
    #pragma unroll
    for (int j = 0; j < 4; ++j) {
        int i = t * 4 + j;
        if (i < NB) { int tmp = v[j]; bsum[i] = excl; excl += tmp; }
    }
}

__global__ __launch_bounds__(256) void k_scan_c(const int* __restrict__ count, int NE,
                                                const int* __restrict__ bsum,
                                                int* __restrict__ rowstart, int E) {
    __shared__ int sh[256];
    int b = blockIdx.x, t = threadIdx.x;
    int base = b * 1024 + t * 4;
    int v[4]; int s = 0;
    #pragma unroll
    for (int j = 0; j < 4; ++j) { int i = base + j; v[j] = (i < NE) ? count[i] : 0; s += v[j]; }
    int incl = block_incl_scan256(s, sh, t);
    int excl = bsum[b] + incl - s;
    #pragma unroll
    for (int j = 0; j < 4; ++j) {
        int i = base + j;
        if (i < NE) { rowstart[i] = excl; excl += v[j]; }
    }
    if (b == 0 && t == 0) rowstart[NE] = E;
}

// ---------------- edge pass 2: score -> exp -> CSR scatter {(r<<17)|t, ev} --
// Atomic-free: rank precomputed in pass 1. No max shift (|score| <~ 6, fp32
// exp safe; softmax shift-invariant). t < 2^17 (NE=100k), r < 2^10 (NR=1000).
__global__ void k_score_scatter(const int* __restrict__ h, const int* __restrict__ r,
                                const int* __restrict__ t, const float* __restrict__ s1,
                                const float* __restrict__ s2, const float* __restrict__ s3,
                                const float* __restrict__ a_b,
                                const int* __restrict__ rowstart, const int* __restrict__ rank,
                                uint2* __restrict__ rt_s, int E) {
    int e = blockIdx.x * blockDim.x + threadIdx.x;
    if (e >= E) return;
    int hi = h[e], ri = r[e], ti = t[e];
    float x = s1[hi] + s2[ri] + s3[ti] + a_b[0];
    float sc = (x >= 0.f) ? x : ALPHA2 * x;
    float ev = __expf(sc);
    rt_s[rowstart[hi] + rank[e]] = make_uint2(((unsigned)ri << 17) | (unsigned)ti,
                                              __float_as_uint(ev));
}

// ---------------- per-entity aggregation: 16 lanes per entity ---------------
// 4 entities per wave -> 4x gather-level parallelism; 16B loads per lane.
// denom = sum of ev computed in-lane (broadcast loads) - no atomics.
__global__ __launch_bounds__(256) void k_aggregate(const int* __restrict__ rowstart,
                                                   const uint2* __restrict__ rt_s,
                                                   const unsigned short* __restrict__ Pb,
                                                   const unsigned short* __restrict__ Qb,
                                                   const unsigned short* __restrict__ Rb,
                                                   const float* __restrict__ bias,
                                                   float* __restrict__ out, int NE) {
    int gid = blockIdx.x * blockDim.x + threadIdx.x;
    int n = gid >> 4;        // entity
    int sl = gid & 15;       // sublane: covers 8 of 128 cols
    if (n >= NE) return;
    int start = rowstart[n], end = rowstart[n + 1];
    int c0 = sl * 8;
    float acc[8] = {};
    float evsum = 0.f;
    int i = start;
    for (; i + 2 <= end; i += 2) {
        uint2 m0 = rt_s[i], m1 = rt_s[i + 1];
        float ev0 = __uint_as_float(m0.y), ev1 = __uint_as_float(m1.y);
        unsigned t0 = m0.x & 0x1FFFFu, r0 = m0.x >> 17;
        unsigned t1 = m1.x & 0x1FFFFu, r1 = m1.x >> 17;
        ushort8 q0 = *(const ushort8*)(Qb + (size_t)t0 * 128 + c0);
        ushort8 rr0 = *(const ushort8*)(Rb + (size_t)r0 * 128 + c0);
        ushort8 q1 = *(const ushort8*)(Qb + (size_t)t1 * 128 + c0);
        ushort8 rr1 = *(const ushort8*)(Rb + (size_t)r1 * 128 + c0);
        evsum += ev0 + ev1;
        #pragma unroll
        for (int j = 0; j < 8; ++j)
            acc[j] = fmaf(ev0, bf2f(q0[j]) + bf2f(rr0[j]), acc[j]);
        #pragma unroll
        for (int j = 0; j < 8; ++j)
            acc[j] = fmaf(ev1, bf2f(q1[j]) + bf2f(rr1[j]), acc[j]);
    }
    if (i < end) {
        uint2 m0 = rt_s[i];
        float ev0 = __uint_as_float(m0.y);
        unsigned t0 = m0.x & 0x1FFFFu, r0 = m0.x >> 17;
        ushort8 q0 = *(const ushort8*)(Qb + (size_t)t0 * 128 + c0);
        ushort8 rr0 = *(const ushort8*)(Rb + (size_t)r0 * 128 + c0);
        evsum += ev0;
        #pragma unroll
        for (int j = 0; j < 8; ++j)
            acc[j] = fmaf(ev0, bf2f(q0[j]) + bf2f(rr0[j]), acc[j]);
    }
    float4 b0 = *(const float4*)(bias + c0);
    float4 b1 = *(const float4*)(bias + c0 + 4);
    float bi[8] = {b0.x, b0.y, b0.z, b0.w, b1.x, b1.y, b1.z, b1.w};
    float o[8];
    if (end > start) {
        float inv = 1.f / evsum;
        ushort8 pb = *(const ushort8*)(Pb + (size_t)n * 128 + c0);
        #pragma unroll
        for (int j = 0; j < 8; ++j) o[j] = bf2f(pb[j]) + acc[j] * inv + bi[j];
    } else {
        #pragma unroll
        for (int j = 0; j < 8; ++j) o[j] = bi[j];
    }
    #pragma unroll
    for (int j = 0; j < 8; ++j) o[j] = fmaxf(o[j], 0.f);
    float* op = out + (size_t)n * 128 + c0;
    *(float4*)(op)     = make_float4(o[0], o[1], o[2], o[3]);
    *(float4*)(op + 4) = make_float4(o[4], o[5], o[6], o[7]);
}

// ============================================================================
static inline size_t align_up(size_t x, size_t a) { return (x + a - 1) / a * a; }

extern "C" void kernel_launch(void* const* d_in, const int* in_sizes, int n_in,
                              void* d_out, int out_size, void* d_ws, size_t ws_size,
                              hipStream_t stream) {
    const int* h_index = (const int*)d_in[0];
    const int* r_index = (const int*)d_in[1];
    const int* t_index = (const int*)d_in[2];
    const float* ent = (const float*)d_in[3];
    const float* rel = (const float*)d_in[4];
    const float* W = (const float*)d_in[5];
    const float* a = (const float*)d_in[6];
    const float* a_b = (const float*)d_in[7];
    const float* bias = (const float*)d_in[8];
    float* out = (float*)d_out;

    int E = in_sizes[0];
    int NE = in_sizes[3] / 128;
    int NR = in_sizes[4] / 128;

    char* p = (char*)d_ws;
    auto alloc = [&](size_t bytes) { char* q = p; p += align_up(bytes, 256); return (void*)q; };
    unsigned short* Pb = (unsigned short*)alloc((size_t)NE * 128 * 2);
    unsigned short* Qb = (unsigned short*)alloc((size_t)NE * 128 * 2);
    unsigned short* Rb = (unsigned short*)alloc((size_t)NR * 128 * 2);
    unsigned short* Wt = (unsigned short*)alloc((size_t)128 * 384 * 2);
    float* s1 = (float*)alloc((size_t)NE * 4);
    float* s3 = (float*)alloc((size_t)NE * 4);
    float* s2 = (float*)alloc((size_t)NR * 4);
    int* count = (int*)alloc((size_t)NE * 4);
    int* rowstart = (int*)alloc((size_t)(NE + 1) * 4);
    int* rank = (int*)alloc((size_t)E * 4);
    int NB = (NE + 1023) / 1024;
    int* bsum = (int*)alloc((size_t)NB * 4);
    uint2* rt_s = (uint2*)alloc((size_t)E * 8);
    (void)ws_size; (void)n_in; (void)out_size;

    // 1. prep: W transpose/cast + zero counters
    int nprep = (NE > 384 * 128) ? NE : 384 * 128;
    k_prep<<<(nprep + 255) / 256, 256, 0, stream>>>(W, Wt, count, NE);
    // 2. edge pass 1: degree count + rank (independent of GEMMs)
    k_count<<<(E + 255) / 256, 256, 0, stream>>>(h_index, count, rank, E);
    // 3. Pb = ent@W1 (+s1) and Qb = ent@W3 (+s3) from one A-stage
    k_gemm<true><<<(NE + 127) / 128, 256, 0, stream>>>(ent, Wt, 0, Pb, s1, 256, Qb, s3, NE, a);
    // 4. Rb = rel@W2 (+s2)
    k_gemm<false><<<(NR + 127) / 128, 256, 0, stream>>>(rel, Wt, 128, Rb, s2, 0, nullptr, nullptr, NR, a);
    // 5-7. scan -> rowstart
    k_scan_a<<<NB, 256, 0, stream>>>(count, NE, bsum);
    k_scan_b<<<1, 256, 0, stream>>>(bsum, NB);
    k_scan_c<<<NB, 256, 0, stream>>>(count, NE, bsum, rowstart, E);
    // 8. edge pass 2: score -> exp -> CSR scatter (atomic-free, packed 8B)
    k_score_scatter<<<(E + 255) / 256, 256, 0, stream>>>(h_index, r_index, t_index,
                                                         s1, s2, s3, a_b, rowstart,
                                                         rank, rt_s, E);
    // 9. aggregate + bias + relu (16 lanes/entity, denom in-register)
    k_aggregate<<<(NE * 16 + 255) / 256, 256, 0, stream>>>(rowstart, rt_s, Pb, Qb, Rb,
                                                           bias, out, NE);
}